// Round 7
// baseline (531.661 us; speedup 1.0000x reference)
//
#include <hip/hip_runtime.h>
#include <math.h>

typedef unsigned char  u8;
typedef unsigned short u16;
typedef unsigned int   u32;
typedef unsigned short u16x8 __attribute__((ext_vector_type(8)));
typedef __bf16 bf16x8 __attribute__((ext_vector_type(8)));
typedef float f32x4 __attribute__((ext_vector_type(4)));

typedef __attribute__((address_space(1))) const unsigned int gu32;
typedef __attribute__((address_space(3))) unsigned int su32;

#define B_ 8
#define C_ 2048
#define MID_ 512
#define N_ 2304

#define BAR() do { asm volatile("" ::: "memory"); __builtin_amdgcn_s_barrier(); asm volatile("" ::: "memory"); } while (0)

#define QMFMA(AV, BV, MO, NO)                                                             \
  { _Pragma("unroll") for (int mfi = 0; mfi < 4; ++mfi) {                                 \
      _Pragma("unroll") for (int nfi = 0; nfi < 2; ++nfi) {                               \
        acc[MO + mfi][NO + nfi] = __builtin_amdgcn_mfma_f32_16x16x32_bf16(                \
            AV[0][mfi], BV[0][nfi], acc[MO + mfi][NO + nfi], 0, 0, 0);                    \
        acc[MO + mfi][NO + nfi] = __builtin_amdgcn_mfma_f32_16x16x32_bf16(                \
            AV[1][mfi], BV[1][nfi], acc[MO + mfi][NO + nfi], 0, 0, 0); } } }

#define QMFMA8(AV, BV, MO, NO)                                                            \
  { _Pragma("unroll") for (int mfi = 0; mfi < 4; ++mfi) {                                 \
      _Pragma("unroll") for (int nfi = 0; nfi < 2; ++nfi) {                               \
        acc[MO + mfi][NO + nfi] = __builtin_amdgcn_mfma_f32_16x16x32_fp8_fp8(             \
            AV[0][mfi], BV[0][nfi], acc[MO + mfi][NO + nfi], 0, 0, 0);                    \
        acc[MO + mfi][NO + nfi] = __builtin_amdgcn_mfma_f32_16x16x32_fp8_fp8(             \
            AV[1][mfi], BV[1][nfi], acc[MO + mfi][NO + nfi], 0, 0, 0); } } }

static __device__ __forceinline__ u16 f2bf(float f) {
  union { float f; unsigned u; } c; c.f = f;
  unsigned u = c.u;
  u += 0x7fffu + ((u >> 16) & 1u);
  return (u16)(u >> 16);
}
static __device__ __forceinline__ float bf2f(u16 x) {
  union { unsigned u; float f; } c; c.u = ((unsigned)x) << 16; return c.f;
}
static __device__ __forceinline__ u32 pk4_fp8(float a, float b, float c, float d) {
  u32 lo = __builtin_amdgcn_cvt_pk_fp8_f32(a, b, 0, false);
  return __builtin_amdgcn_cvt_pk_fp8_f32(c, d, lo, true);
}
static __device__ __forceinline__ u8 f2fp8(float a) {
  return (u8)(__builtin_amdgcn_cvt_pk_fp8_f32(a, a, 0, false) & 0xff);
}

// ---------------- prep kernels ----------------
// Wall8 [1536][2048] fp8 (f,g,h weights) and vwb8 [2048][512] fp8, one kernel.
__global__ __launch_bounds__(256) void prep_w8_k(
    const float* __restrict__ fw, const float* __restrict__ gw,
    const float* __restrict__ hw, const float* __restrict__ vw,
    u8* __restrict__ wall8, u8* __restrict__ vw8) {
  int w = blockIdx.x * 256 + threadIdx.x;     // 16B... 4-elem word index
  float4 v; u8* dst;
  if (w < 786432) {                            // 1536*2048/4
    int e = w * 4; int r = e >> 11;
    const float* s = (r < 512) ? (fw + e) : (r < 1024) ? (gw + e - (512 << 11)) : (hw + e - (1024 << 11));
    v = *(const float4*)s; dst = wall8 + e;
  } else if (w < 786432 + 262144) {            // + 2048*512/4
    int e = (w - 786432) * 4;
    v = *(const float4*)(vw + e); dst = vw8 + e;
  } else return;
  *(u32*)dst = pk4_fp8(v.x, v.y, v.z, v.w);
}

// BN fold; f-columns pre-scaled by 512^-0.5
__global__ __launch_bounds__(256) void prep_sb_k(
    const float* fb, const float* fg, const float* fbe, const float* fm, const float* fv,
    const float* gb, const float* gg, const float* gbe, const float* gm, const float* gv,
    const float* hb, float* __restrict__ scale, float* __restrict__ bias) {
  int i = blockIdx.x * 256 + threadIdx.x;
  if (i >= 1536) return;
  const float FS = 0.044194173824159216f;
  if (i < 512) {
    float inv = fg[i] / sqrtf(fv[i] + 1e-5f);
    scale[i] = inv * FS; bias[i] = (fb[i] * inv + fbe[i] - fm[i] * inv) * FS;
  } else if (i < 1024) {
    int j = i - 512;
    float inv = gg[j] / sqrtf(gv[j] + 1e-5f);
    scale[i] = inv; bias[i] = gb[j] * inv + gbe[j] - gm[j] * inv;
  } else {
    scale[i] = 1.0f; bias[i] = hb[i - 1024];
  }
}

// x [B][C][N] f32 -> xT8 [B][N][C] fp8   (64x64 tile)
__global__ __launch_bounds__(256) void transpose_x_k(const float* __restrict__ x, u8* __restrict__ xT) {
  __shared__ float tile[64][68];
  const int b = blockIdx.z;
  const int n0 = blockIdx.x * 64, c0 = blockIdx.y * 64;
  const float* xb = x + (size_t)b * C_ * N_;
  u8* xTb = xT + (size_t)b * N_ * C_;
  const int r = threadIdx.x >> 2, q = threadIdx.x & 3;
  #pragma unroll
  for (int j = 0; j < 4; ++j) {
    float4 v = *(const float4*)&xb[(size_t)(c0 + r) * N_ + n0 + (q + 4 * j) * 4];
    *(float4*)&tile[r][(q + 4 * j) * 4] = v;
  }
  __syncthreads();
  #pragma unroll
  for (int g = 0; g < 2; ++g) {
    const int cl = (q * 2 + g) * 8;
    uint2 w;
    w.x = pk4_fp8(tile[cl + 0][r], tile[cl + 1][r], tile[cl + 2][r], tile[cl + 3][r]);
    w.y = pk4_fp8(tile[cl + 4][r], tile[cl + 5][r], tile[cl + 6][r], tile[cl + 7][r]);
    *(uint2*)&xTb[(size_t)(n0 + r) * C_ + c0 + cl] = w;
  }
}

// fghT h-columns [B][N][1024+c] bf16 -> hx [B][512][N] bf16
__global__ __launch_bounds__(256) void transpose_h_k(const u16* __restrict__ fghT, u16* __restrict__ hx) {
  __shared__ u16 tile[32][33];
  const int b = blockIdx.z;
  const int n0 = blockIdx.x * 32, c0 = blockIdx.y * 32;
  const u16* src = fghT + (size_t)b * N_ * 1536;
  u16* dst = hx + (size_t)b * MID_ * N_;
  const int tx = threadIdx.x & 31, ty = threadIdx.x >> 5;
  #pragma unroll
  for (int i = 0; i < 4; ++i)
    tile[ty + i * 8][tx] = src[(size_t)(n0 + ty + i * 8) * 1536 + 1024 + c0 + tx];
  __syncthreads();
  #pragma unroll
  for (int i = 0; i < 4; ++i)
    dst[(size_t)(c0 + ty + i * 8) * N_ + n0 + tx] = tile[tx][ty + i * 8];
}

#define EP_FG 0       // v*scale[col]+bias[col], relu if col<1024, store bf16
#define EP_SCALE16 1  // f2bf(v)
#define EP_FINAL 2    // v+bias[row]+x[row][col], store f32
#define EP_FP8 3      // f2fp8(v)

// ---------------- bf16 GEMM (unchanged engine; G2/G3) ----------------
template<int EPI, int SWZ, int GX, int GY>
__global__ __launch_bounds__(512, 2) void gemm5_kernel(
    const u16* __restrict__ Ag, int lda, long long sA,
    const u16* __restrict__ Bg, int ldb, long long sB,
    void* __restrict__ Cg, int ldc, long long sC, int K,
    const float* __restrict__ ep_scale, const float* __restrict__ ep_bias,
    const float* __restrict__ ep_x, long long sX)
{
  extern __shared__ __align__(16) u16 smem[];
  u16* As = smem;
  u16* Bs = smem + 2 * 256 * 64;

  int tx, ty, tz;
  {
    const int L = blockIdx.x;
    const int xcd = L & 7, r = L >> 3;
    if constexpr (SWZ == 0) {
      const int i = r % GX, j = (r / GX) * 8 + xcd;
      tx = i; ty = j % GY; tz = j / GY;
    } else if constexpr (SWZ == 1) {
      const int i = r % GY, j = (r / GY) * 8 + xcd;
      ty = i; tx = j % GX; tz = j / GX;
    } else {
      const int i = r % 9, jg = (r / 9) * 8 + xcd;
      const int bx = jg % (GX / 3), rem = jg / (GX / 3);
      const int by = rem % (GY / 3); tz = rem / (GY / 3);
      tx = bx * 3 + i % 3; ty = by * 3 + i / 3;
    }
  }

  const int tid = threadIdx.x;
  const int lane = tid & 63;
  const int wv = tid >> 6;
  const int b = tz;
  const int m0 = ty * 256;
  const int n0 = tx * 256;
  const int wm = (wv >> 2) * 128;
  const int wn = (wv & 3) * 64;
  const int lr = lane & 15, lg = lane >> 4;

  const u16* Ab = Ag + (size_t)b * sA;
  const u16* Bb = Bg + (size_t)b * sB;
  const int nk = K >> 6;

  const int srow = lane >> 3;
  const int sksw = ((lane & 7) ^ srow) * 8;
  const int rdsw0 = ((0 + lg) ^ (lr & 7)) * 8;
  const int rdsw1 = ((4 + lg) ^ (lr & 7)) * 8;

  f32x4 acc[8][4];
  #pragma unroll
  for (int i = 0; i < 8; ++i)
    #pragma unroll
    for (int j = 0; j < 4; ++j)
      acc[i][j] = f32x4{0.f, 0.f, 0.f, 0.f};

  auto STAGE_A = [&](int p2, int t) {
    #pragma unroll
    for (int j = 0; j < 4; ++j) {
      const int rb = j * 64 + wv * 8;
      const u16* g = Ab + (size_t)(m0 + rb + srow) * lda + t * 64 + sksw;
      __builtin_amdgcn_global_load_lds((gu32*)g, (su32*)(As + p2 * 16384 + rb * 64), 16, 0, 0);
    }
  };
  auto STAGE_B = [&](int p2, int t) {
    #pragma unroll
    for (int j = 0; j < 4; ++j) {
      const int rb = j * 64 + wv * 8;
      const u16* g = Bb + (size_t)(n0 + rb + srow) * ldb + t * 64 + sksw;
      __builtin_amdgcn_global_load_lds((gu32*)g, (su32*)(Bs + p2 * 16384 + rb * 64), 16, 0, 0);
    }
  };

  STAGE_A(0, 0); STAGE_B(0, 0);
  if (nk > 1) { STAGE_A(1, 1); STAGE_B(1, 1); }

  for (int kt = 0; kt < nk; ++kt) {
    const int p = kt & 1;
    if (kt + 1 < nk) asm volatile("s_waitcnt vmcnt(8)" ::: "memory");
    else             asm volatile("s_waitcnt vmcnt(0)" ::: "memory");
    BAR();

    const u16* Asl = As + p * 16384;
    const u16* Bsl = Bs + p * 16384;
    const bool st = (kt + 2) < nk;
    const int ps = (kt + 2) & 1;

    bf16x8 aV[2][4], bLo[2][2], bHi[2][2];

    #pragma unroll
    for (int ks = 0; ks < 2; ++ks) {
      const int ro = ks ? rdsw1 : rdsw0;
      #pragma unroll
      for (int i = 0; i < 4; ++i)
        aV[ks][i] = *(const bf16x8*)(Asl + (wm + i * 16 + lr) * 64 + ro);
      #pragma unroll
      for (int i = 0; i < 2; ++i)
        bLo[ks][i] = *(const bf16x8*)(Bsl + (wn + i * 16 + lr) * 64 + ro);
    }
    BAR();
    __builtin_amdgcn_s_setprio(1);
    QMFMA(aV, bLo, 0, 0);
    __builtin_amdgcn_s_setprio(0);
    BAR();

    #pragma unroll
    for (int ks = 0; ks < 2; ++ks) {
      const int ro = ks ? rdsw1 : rdsw0;
      #pragma unroll
      for (int i = 0; i < 2; ++i)
        bHi[ks][i] = *(const bf16x8*)(Bsl + (wn + 32 + i * 16 + lr) * 64 + ro);
    }
    BAR();
    __builtin_amdgcn_s_setprio(1);
    QMFMA(aV, bHi, 0, 2);
    __builtin_amdgcn_s_setprio(0);
    BAR();

    #pragma unroll
    for (int ks = 0; ks < 2; ++ks) {
      const int ro = ks ? rdsw1 : rdsw0;
      #pragma unroll
      for (int i = 0; i < 4; ++i)
        aV[ks][i] = *(const bf16x8*)(Asl + (wm + 64 + i * 16 + lr) * 64 + ro);
    }
    if (st) STAGE_B(ps, kt + 2);
    BAR();
    __builtin_amdgcn_s_setprio(1);
    QMFMA(aV, bLo, 4, 0);
    __builtin_amdgcn_s_setprio(0);
    BAR();

    if (st) STAGE_A(ps, kt + 2);
    BAR();
    __builtin_amdgcn_s_setprio(1);
    QMFMA(aV, bHi, 4, 2);
    __builtin_amdgcn_s_setprio(0);
    BAR();
  }

  u16*   C16 = (u16*)Cg + (size_t)b * sC;
  float* C32 = (float*)Cg + (size_t)b * sC;
  u8*    C8  = (u8*)Cg  + (size_t)b * sC;
  const float* xb = (EPI == EP_FINAL) ? (ep_x + (size_t)b * sX) : nullptr;
  #pragma unroll
  for (int mf = 0; mf < 8; ++mf) {
    #pragma unroll
    for (int nf = 0; nf < 4; ++nf) {
      #pragma unroll
      for (int r = 0; r < 4; ++r) {
        int row = m0 + wm + mf * 16 + lg * 4 + r;
        int col = n0 + wn + nf * 16 + lr;
        float v = acc[mf][nf][r];
        if constexpr (EPI == EP_FG) {
          v = v * ep_scale[col] + ep_bias[col];
          if (col < 1024) v = fmaxf(v, 0.f);
          C16[(size_t)row * ldc + col] = f2bf(v);
        } else if constexpr (EPI == EP_SCALE16) {
          C16[(size_t)row * ldc + col] = f2bf(v);
        } else if constexpr (EPI == EP_FP8) {
          C8[(size_t)row * ldc + col] = f2fp8(v);
        } else {
          v += ep_bias[row] + xb[(size_t)row * ldc + col];
          C32[(size_t)row * ldc + col] = v;
        }
      }
    }
  }
}

// ---------------- fp8 GEMM (G1/G5): same 4-phase structure, 1B elems, 64KB LDS --------
// LDS cell (row, chunk16B c) holds global chunk c ^ (row&3); ds_read_b64 slot
// s = ks*4+lg read at s ^ ((row&3)<<1) -> 4 dwords/bank (ideal). Stage: 2 instr/wave
// per operand per K-tile -> vmcnt(4) steady state.
template<int EPI, int SWZ, int GX, int GY>
__global__ __launch_bounds__(512, 2) void gemm8_kernel(
    const u8* __restrict__ Ag, int lda, long long sA,
    const u8* __restrict__ Bg, int ldb, long long sB,
    void* __restrict__ Cg, int ldc, long long sC, int K,
    const float* __restrict__ ep_scale, const float* __restrict__ ep_bias,
    const float* __restrict__ ep_x, long long sX)
{
  extern __shared__ __align__(16) u8 smem8[];
  u8* As = smem8;                    // [2][256*64]
  u8* Bs = smem8 + 2 * 256 * 64;

  int tx, ty, tz;
  {
    const int L = blockIdx.x;
    const int xcd = L & 7, r = L >> 3;
    if constexpr (SWZ == 0) {
      const int i = r % GX, j = (r / GX) * 8 + xcd;
      tx = i; ty = j % GY; tz = j / GY;
    } else {
      const int i = r % GY, j = (r / GY) * 8 + xcd;
      ty = i; tx = j % GX; tz = j / GX;
    }
  }

  const int tid = threadIdx.x;
  const int lane = tid & 63;
  const int wv = tid >> 6;
  const int b = tz;
  const int m0 = ty * 256;
  const int n0 = tx * 256;
  const int wm = (wv >> 2) * 128;
  const int wn = (wv & 3) * 64;
  const int lr = lane & 15, lg = lane >> 4;

  const u8* Ab = Ag + (size_t)b * sA;
  const u8* Bb = Bg + (size_t)b * sB;
  const int nk = K >> 6;

  const int s16row = lane >> 2;                        // 0..15
  const int schunk = ((lane & 3) ^ (s16row & 3)) * 16; // byte offset, pre-swizzled source
  const int oA = (lg ^ ((lr & 3) << 1)) * 8;           // ks=0 slot byte offset; ks=1: ^32

  f32x4 acc[8][4];
  #pragma unroll
  for (int i = 0; i < 8; ++i)
    #pragma unroll
    for (int j = 0; j < 4; ++j)
      acc[i][j] = f32x4{0.f, 0.f, 0.f, 0.f};

  auto STAGE_A = [&](int p2, int t) {
    #pragma unroll
    for (int j = 0; j < 2; ++j) {
      const int rb = j * 128 + wv * 16;
      const u8* g = Ab + (size_t)(m0 + rb + s16row) * lda + t * 64 + schunk;
      __builtin_amdgcn_global_load_lds((gu32*)g, (su32*)(As + p2 * 16384 + rb * 64), 16, 0, 0);
    }
  };
  auto STAGE_B = [&](int p2, int t) {
    #pragma unroll
    for (int j = 0; j < 2; ++j) {
      const int rb = j * 128 + wv * 16;
      const u8* g = Bb + (size_t)(n0 + rb + s16row) * ldb + t * 64 + schunk;
      __builtin_amdgcn_global_load_lds((gu32*)g, (su32*)(Bs + p2 * 16384 + rb * 64), 16, 0, 0);
    }
  };

  STAGE_A(0, 0); STAGE_B(0, 0);
  if (nk > 1) { STAGE_A(1, 1); STAGE_B(1, 1); }

  for (int kt = 0; kt < nk; ++kt) {
    const int p = kt & 1;
    if (kt + 1 < nk) asm volatile("s_waitcnt vmcnt(4)" ::: "memory");
    else             asm volatile("s_waitcnt vmcnt(0)" ::: "memory");
    BAR();

    const u8* Asl = As + p * 16384;
    const u8* Bsl = Bs + p * 16384;
    const bool st = (kt + 2) < nk;
    const int ps = (kt + 2) & 1;

    long aV[2][4], bLo[2][2], bHi[2][2];

    #pragma unroll
    for (int ks = 0; ks < 2; ++ks) {
      const int ro = oA ^ (ks * 32);
      #pragma unroll
      for (int i = 0; i < 4; ++i)
        aV[ks][i] = *(const long*)(Asl + (wm + i * 16 + lr) * 64 + ro);
      #pragma unroll
      for (int i = 0; i < 2; ++i)
        bLo[ks][i] = *(const long*)(Bsl + (wn + i * 16 + lr) * 64 + ro);
    }
    BAR();
    __builtin_amdgcn_s_setprio(1);
    QMFMA8(aV, bLo, 0, 0);
    __builtin_amdgcn_s_setprio(0);
    BAR();

    #pragma unroll
    for (int ks = 0; ks < 2; ++ks) {
      const int ro = oA ^ (ks * 32);
      #pragma unroll
      for (int i = 0; i < 2; ++i)
        bHi[ks][i] = *(const long*)(Bsl + (wn + 32 + i * 16 + lr) * 64 + ro);
    }
    BAR();
    __builtin_amdgcn_s_setprio(1);
    QMFMA8(aV, bHi, 0, 2);
    __builtin_amdgcn_s_setprio(0);
    BAR();

    #pragma unroll
    for (int ks = 0; ks < 2; ++ks) {
      const int ro = oA ^ (ks * 32);
      #pragma unroll
      for (int i = 0; i < 4; ++i)
        aV[ks][i] = *(const long*)(Asl + (wm + 64 + i * 16 + lr) * 64 + ro);
    }
    if (st) STAGE_B(ps, kt + 2);
    BAR();
    __builtin_amdgcn_s_setprio(1);
    QMFMA8(aV, bLo, 4, 0);
    __builtin_amdgcn_s_setprio(0);
    BAR();

    if (st) STAGE_A(ps, kt + 2);
    BAR();
    __builtin_amdgcn_s_setprio(1);
    QMFMA8(aV, bHi, 4, 2);
    __builtin_amdgcn_s_setprio(0);
    BAR();
  }

  u16*   C16 = (u16*)Cg + (size_t)b * sC;
  float* C32 = (float*)Cg + (size_t)b * sC;
  const float* xb = (EPI == EP_FINAL) ? (ep_x + (size_t)b * sX) : nullptr;
  #pragma unroll
  for (int mf = 0; mf < 8; ++mf) {
    #pragma unroll
    for (int nf = 0; nf < 4; ++nf) {
      #pragma unroll
      for (int r = 0; r < 4; ++r) {
        int row = m0 + wm + mf * 16 + lg * 4 + r;
        int col = n0 + wn + nf * 16 + lr;
        float v = acc[mf][nf][r];
        if constexpr (EPI == EP_FG) {
          v = v * ep_scale[col] + ep_bias[col];
          if (col < 1024) v = fmaxf(v, 0.f);
          C16[(size_t)row * ldc + col] = f2bf(v);
        } else {
          v += ep_bias[row] + xb[(size_t)row * ldc + col];
          C32[(size_t)row * ldc + col] = v;
        }
      }
    }
  }
}

// -------- softmax: bf16 scores -> f32 attn + bf16 P in place --------
__global__ __launch_bounds__(256) void softmax_k(u16* __restrict__ SP, float* __restrict__ attn) {
  u16* sp = SP + (size_t)blockIdx.x * N_;
  float* ar = attn + (size_t)blockIdx.x * N_;
  const int tid = threadIdx.x;
  u16x8 s8 = *(const u16x8*)&sp[tid * 8];
  u16 st = sp[2048 + tid];
  float w[8], wt = bf2f(st);
  #pragma unroll
  for (int j = 0; j < 8; ++j) w[j] = bf2f(s8[j]);
  float mx = wt;
  #pragma unroll
  for (int j = 0; j < 8; ++j) mx = fmaxf(mx, w[j]);
  #pragma unroll
  for (int o = 32; o; o >>= 1) mx = fmaxf(mx, __shfl_xor(mx, o));
  __shared__ float red[4], red2[4];
  if ((tid & 63) == 0) red[tid >> 6] = mx;
  __syncthreads();
  mx = fmaxf(fmaxf(red[0], red[1]), fmaxf(red[2], red[3]));
  float s = 0.f;
  #pragma unroll
  for (int j = 0; j < 8; ++j) { w[j] = __expf(w[j] - mx); s += w[j]; }
  wt = __expf(wt - mx); s += wt;
  #pragma unroll
  for (int o = 32; o; o >>= 1) s += __shfl_xor(s, o);
  if ((tid & 63) == 0) red2[tid >> 6] = s;
  __syncthreads();
  s = red2[0] + red2[1] + red2[2] + red2[3];
  float inv = 1.0f / s;
  #pragma unroll
  for (int j = 0; j < 8; ++j) w[j] *= inv;
  wt *= inv;
  float4 o0 = {w[0], w[1], w[2], w[3]}, o1 = {w[4], w[5], w[6], w[7]};
  *(float4*)&ar[tid * 8] = o0;
  *(float4*)&ar[tid * 8 + 4] = o1;
  ar[2048 + tid] = wt;
  u16x8 p8;
  #pragma unroll
  for (int j = 0; j < 8; ++j) p8[j] = f2bf(w[j]);
  *(u16x8*)&sp[tid * 8] = p8;
  sp[2048 + tid] = f2bf(wt);
}

// ---------------- launch ----------------
extern "C" void kernel_launch(void* const* d_in, const int* in_sizes, int n_in,
                              void* d_out, int out_size, void* d_ws, size_t ws_size,
                              hipStream_t stream) {
  const float* x    = (const float*)d_in[0];
  const float* f_w  = (const float*)d_in[1];
  const float* f_b  = (const float*)d_in[2];
  const float* f_ga = (const float*)d_in[3];
  const float* f_be = (const float*)d_in[4];
  const float* f_me = (const float*)d_in[5];
  const float* f_va = (const float*)d_in[6];
  const float* g_w  = (const float*)d_in[7];
  const float* g_b  = (const float*)d_in[8];
  const float* g_ga = (const float*)d_in[9];
  const float* g_be = (const float*)d_in[10];
  const float* g_me = (const float*)d_in[11];
  const float* g_va = (const float*)d_in[12];
  const float* h_w  = (const float*)d_in[13];
  const float* h_b  = (const float*)d_in[14];
  const float* v_w  = (const float*)d_in[15];
  const float* v_b  = (const float*)d_in[16];

  float* out0 = (float*)d_out;
  float* attn = out0 + (size_t)B_ * C_ * N_;

  // workspace carve
  char* p = (char*)d_ws;
  u8*  xT8  = (u8*)p;  p += (size_t)B_ * N_ * C_;           // 37.7 MB fp8
  u16* fghT = (u16*)p; p += (size_t)B_ * N_ * 1536 * 2;     // 56.6 MB bf16
  u16* hx   = (u16*)p; p += (size_t)B_ * MID_ * N_ * 2;     // 18.9 MB bf16
  u8*  ZT8  = (u8*)p;  p += (size_t)B_ * N_ * MID_;         // 9.4 MB fp8
  u8*  Wall8= (u8*)p;  p += (size_t)1536 * C_;              // 3.1 MB fp8
  u8*  vwb8 = (u8*)p;  p += (size_t)C_ * MID_;              // 1.0 MB fp8
  float* sc = (float*)p; p += 1536 * 4;
  float* bi = (float*)p; p += 1536 * 4;
  p = (char*)(((size_t)p + 255) & ~(size_t)255);
  u16* SP   = (u16*)p; p += (size_t)B_ * N_ * N_ * 2;       // 85 MB bf16 scores/P

  hipFuncSetAttribute((const void*)gemm5_kernel<EP_SCALE16, 2, 9, 9>, hipFuncAttributeMaxDynamicSharedMemorySize, 131072);
  hipFuncSetAttribute((const void*)gemm5_kernel<EP_FP8, 0, 2, 9>,     hipFuncAttributeMaxDynamicSharedMemorySize, 131072);
  hipFuncSetAttribute((const void*)gemm8_kernel<EP_FG, 0, 6, 9>,      hipFuncAttributeMaxDynamicSharedMemorySize, 65536);
  hipFuncSetAttribute((const void*)gemm8_kernel<EP_FINAL, 1, 9, 8>,   hipFuncAttributeMaxDynamicSharedMemorySize, 65536);

  prep_w8_k<<<(786432 + 262144 + 255) / 256, 256, 0, stream>>>(f_w, g_w, h_w, v_w, Wall8, vwb8);
  prep_sb_k<<<6, 256, 0, stream>>>(f_b, f_ga, f_be, f_me, f_va,
                                   g_b, g_ga, g_be, g_me, g_va, h_b, sc, bi);
  transpose_x_k<<<dim3(N_ / 64, C_ / 64, B_), 256, 0, stream>>>(x, xT8);

  // G1 (fp8): fghT[n][c'] = xT8[n][:].Wall8[c'][:] (M=2304,N=1536,K=2048) -> bf16
  gemm8_kernel<EP_FG, 0, 6, 9><<<dim3(6 * 9 * 8), 512, 65536, stream>>>(
      xT8, C_, (long long)N_ * C_, Wall8, C_, 0,
      fghT, 1536, (long long)N_ * 1536, C_, sc, bi, nullptr, 0);

  transpose_h_k<<<dim3(N_ / 32, MID_ / 32, B_), 256, 0, stream>>>(fghT, hx);

  // G2 (bf16): scores = f.g^T (M=N=2304,K=512) -> bf16 SP
  gemm5_kernel<EP_SCALE16, 2, 9, 9><<<dim3(9 * 9 * 8), 512, 131072, stream>>>(
      fghT, 1536, (long long)N_ * 1536, fghT + 512, 1536, (long long)N_ * 1536,
      SP, N_, (long long)N_ * N_, MID_, nullptr, nullptr, nullptr, 0);

  softmax_k<<<B_ * N_, 256, 0, stream>>>(SP, attn);

  // G3 (bf16 -> fp8 out): ZT8[n][c] = P[n][:].hx[c][:] (M=2304,N=512,K=2304)
  gemm5_kernel<EP_FP8, 0, 2, 9><<<dim3(2 * 9 * 8), 512, 131072, stream>>>(
      SP, N_, (long long)N_ * N_, hx, N_, (long long)MID_ * N_,
      ZT8, MID_, (long long)N_ * MID_, N_, nullptr, nullptr, nullptr, 0);

  // G5 (fp8): out[o][n] = vwb8[o][:].ZT8[n][:] + v_b[o] + x[o][n] (M=2048,N=2304,K=512)
  gemm8_kernel<EP_FINAL, 1, 9, 8><<<dim3(9 * 8 * 8), 512, 65536, stream>>>(
      vwb8, MID_, 0, ZT8, MID_, (long long)N_ * MID_,
      out0, N_, (long long)C_ * N_, MID_, nullptr, v_b, x, (long long)C_ * N_);
}

// Round 8
// 504.300 us; speedup vs baseline: 1.0543x; 1.0543x over previous
//
#include <hip/hip_runtime.h>
#include <math.h>

typedef unsigned short u16;
typedef unsigned short u16x4 __attribute__((ext_vector_type(4)));
typedef unsigned short u16x8 __attribute__((ext_vector_type(8)));
typedef __bf16 bf16x8 __attribute__((ext_vector_type(8)));
typedef float f32x4 __attribute__((ext_vector_type(4)));

typedef __attribute__((address_space(1))) const unsigned int gu32;
typedef __attribute__((address_space(3))) unsigned int su32;

#define B_ 8
#define C_ 2048
#define MID_ 512
#define N_ 2304

#define BAR() do { asm volatile("" ::: "memory"); __builtin_amdgcn_s_barrier(); asm volatile("" ::: "memory"); } while (0)

#define QMFMA(AV, BV, MO, NO)                                                             \
  { _Pragma("unroll") for (int mfi = 0; mfi < 4; ++mfi) {                                 \
      _Pragma("unroll") for (int nfi = 0; nfi < 2; ++nfi) {                               \
        acc[MO + mfi][NO + nfi] = __builtin_amdgcn_mfma_f32_16x16x32_bf16(                \
            AV[0][mfi], BV[0][nfi], acc[MO + mfi][NO + nfi], 0, 0, 0);                    \
        acc[MO + mfi][NO + nfi] = __builtin_amdgcn_mfma_f32_16x16x32_bf16(                \
            AV[1][mfi], BV[1][nfi], acc[MO + mfi][NO + nfi], 0, 0, 0); } } }

static __device__ __forceinline__ u16 f2bf(float f) {
  union { float f; unsigned u; } c; c.f = f;
  unsigned u = c.u;
  u += 0x7fffu + ((u >> 16) & 1u);   // round to nearest even
  return (u16)(u >> 16);
}
static __device__ __forceinline__ float bf2f(u16 x) {
  union { unsigned u; float f; } c; c.u = ((unsigned)x) << 16; return c.f;
}

// ---------------- fused prep: Wall bf16, vwb bf16, BN-fold scale/bias ----------------
// Wall rows 0..511 = f_w, 512..1023 = g_w, 1024..1535 = h_w  (contiguous K=2048)
__global__ __launch_bounds__(256) void prep_all_k(
    const float* __restrict__ fw, const float* __restrict__ gw,
    const float* __restrict__ hw, const float* __restrict__ vw,
    const float* fb, const float* fg, const float* fbe, const float* fm, const float* fv,
    const float* gb, const float* gg, const float* gbe, const float* gm, const float* gv,
    const float* hb,
    u16* __restrict__ wall, u16* __restrict__ vwb,
    float* __restrict__ scale, float* __restrict__ bias) {
  const int gid = blockIdx.x * 256 + threadIdx.x;
  if (gid < 393216) {                       // 1536*2048/8 u16x8 chunks
    int e = gid * 8; int r = e >> 11;
    const float* s = (r < 512) ? (fw + e) : (r < 1024) ? (gw + e - (512 << 11)) : (hw + e - (1024 << 11));
    float4 v0 = *(const float4*)s, v1 = *(const float4*)(s + 4);
    u16x8 w;
    w[0]=f2bf(v0.x); w[1]=f2bf(v0.y); w[2]=f2bf(v0.z); w[3]=f2bf(v0.w);
    w[4]=f2bf(v1.x); w[5]=f2bf(v1.y); w[6]=f2bf(v1.z); w[7]=f2bf(v1.w);
    *(u16x8*)&wall[e] = w;
  } else if (gid < 524288) {                // + 2048*512/8
    int e = (gid - 393216) * 8;
    float4 v0 = *(const float4*)(vw + e), v1 = *(const float4*)(vw + e + 4);
    u16x8 w;
    w[0]=f2bf(v0.x); w[1]=f2bf(v0.y); w[2]=f2bf(v0.z); w[3]=f2bf(v0.w);
    w[4]=f2bf(v1.x); w[5]=f2bf(v1.y); w[6]=f2bf(v1.z); w[7]=f2bf(v1.w);
    *(u16x8*)&vwb[e] = w;
  }
  if (gid < 1536) {
    const float FS = 0.044194173824159216f;  // 512^-0.5 folded into f columns
    int i = gid;
    if (i < 512) {
      float inv = fg[i] / sqrtf(fv[i] + 1e-5f);
      scale[i] = inv * FS; bias[i] = (fb[i] * inv + fbe[i] - fm[i] * inv) * FS;
    } else if (i < 1024) {
      int j = i - 512;
      float inv = gg[j] / sqrtf(gv[j] + 1e-5f);
      scale[i] = inv; bias[i] = gb[j] * inv + gbe[j] - gm[j] * inv;
    } else {
      scale[i] = 1.0f; bias[i] = hb[i - 1024];
    }
  }
}

// x [B][C][N] f32 -> xT [B][N][C] bf16   (64x64 tile, float4 loads, 16B stores)
__global__ __launch_bounds__(256) void transpose_x_k(const float* __restrict__ x, u16* __restrict__ xT) {
  __shared__ float tile[64][68];
  const int b = blockIdx.z;
  const int n0 = blockIdx.x * 64, c0 = blockIdx.y * 64;
  const float* xb = x + (size_t)b * C_ * N_;
  u16* xTb = xT + (size_t)b * N_ * C_;
  const int r = threadIdx.x >> 2, q = threadIdx.x & 3;
  #pragma unroll
  for (int j = 0; j < 4; ++j) {
    float4 v = *(const float4*)&xb[(size_t)(c0 + r) * N_ + n0 + (q + 4 * j) * 4];
    *(float4*)&tile[r][(q + 4 * j) * 4] = v;
  }
  __syncthreads();
  #pragma unroll
  for (int g = 0; g < 2; ++g) {
    const int cl = (q * 2 + g) * 8;
    u16x8 w;
    #pragma unroll
    for (int e = 0; e < 8; ++e) w[e] = f2bf(tile[cl + e][r]);
    *(u16x8*)&xTb[(size_t)(n0 + r) * C_ + c0 + cl] = w;
  }
}

// fghT h-columns [B][N][1024+c] bf16 -> hx [B][512][N] bf16  (64x64 tile, u16x8 both sides)
__global__ __launch_bounds__(256) void transpose_h_k(const u16* __restrict__ fghT, u16* __restrict__ hx) {
  __shared__ u16 tile[64][72];
  const int b = blockIdx.z;
  const int n0 = blockIdx.x * 64, c0 = blockIdx.y * 64;
  const u16* src = fghT + (size_t)b * N_ * 1536;
  u16* dst = hx + (size_t)b * MID_ * N_;
  const int r = threadIdx.x >> 2, q = threadIdx.x & 3;
  #pragma unroll
  for (int g = 0; g < 2; ++g) {
    const int cl = q * 16 + g * 8;
    *(u16x8*)&tile[r][cl] = *(const u16x8*)&src[(size_t)(n0 + r) * 1536 + 1024 + c0 + cl];
  }
  __syncthreads();
  #pragma unroll
  for (int g = 0; g < 2; ++g) {
    const int cl = q * 16 + g * 8;
    u16x8 w;
    #pragma unroll
    for (int e = 0; e < 8; ++e) w[e] = tile[cl + e][r];
    *(u16x8*)&dst[(size_t)(c0 + r) * N_ + n0 + cl] = w;
  }
}

// ---------------- GEMM: 256x256, BK=64, 2-buf LDS, 4-phase, counted vmcnt, XCD groups --
// OUT[M,N] = A[M,K] * B^T[N,K]; bf16 row-major contiguous-K.
#define EP_FG 0       // v*scale[col]+bias[col], relu if col<1024, store bf16
#define EP_SCALE16 1  // f2bf(v)
#define EP_FINAL 2    // v+bias[row]+x[row][col], store f32

template<int EPI, int SWZ, int GX, int GY>
__global__ __launch_bounds__(512, 2) void gemm5_kernel(
    const u16* __restrict__ Ag, int lda, long long sA,
    const u16* __restrict__ Bg, int ldb, long long sB,
    void* __restrict__ Cg, int ldc, long long sC, int K,
    const float* __restrict__ ep_scale, const float* __restrict__ ep_bias,
    const float* __restrict__ ep_x, long long sX)
{
  extern __shared__ __align__(16) u16 smem[];
  u16* As = smem;                    // [2][256*64]
  u16* Bs = smem + 2 * 256 * 64;

  int tx, ty, tz;
  {
    const int L = blockIdx.x;
    const int xcd = L & 7, r = L >> 3;
    if constexpr (SWZ == 0) {
      const int i = r % GX, j = (r / GX) * 8 + xcd;
      tx = i; ty = j % GY; tz = j / GY;
    } else if constexpr (SWZ == 1) {
      const int i = r % GY, j = (r / GY) * 8 + xcd;
      ty = i; tx = j % GX; tz = j / GX;
    } else {
      const int i = r % 9, jg = (r / 9) * 8 + xcd;
      const int bx = jg % (GX / 3), rem = jg / (GX / 3);
      const int by = rem % (GY / 3); tz = rem / (GY / 3);
      tx = bx * 3 + i % 3; ty = by * 3 + i / 3;
    }
  }

  const int tid = threadIdx.x;
  const int lane = tid & 63;
  const int wv = tid >> 6;
  const int b = tz;
  const int m0 = ty * 256;
  const int n0 = tx * 256;
  const int wm = (wv >> 2) * 128;
  const int wn = (wv & 3) * 64;
  const int lr = lane & 15, lg = lane >> 4;

  const u16* Ab = Ag + (size_t)b * sA;
  const u16* Bb = Bg + (size_t)b * sB;
  const int nk = K >> 6;

  const int srow = lane >> 3;
  const int sksw = ((lane & 7) ^ srow) * 8;
  const int rdsw0 = ((0 + lg) ^ (lr & 7)) * 8;
  const int rdsw1 = ((4 + lg) ^ (lr & 7)) * 8;

  f32x4 acc[8][4];
  #pragma unroll
  for (int i = 0; i < 8; ++i)
    #pragma unroll
    for (int j = 0; j < 4; ++j)
      acc[i][j] = f32x4{0.f, 0.f, 0.f, 0.f};

  auto STAGE_A = [&](int p2, int t) {
    #pragma unroll
    for (int j = 0; j < 4; ++j) {
      const int rb = j * 64 + wv * 8;
      const u16* g = Ab + (size_t)(m0 + rb + srow) * lda + t * 64 + sksw;
      __builtin_amdgcn_global_load_lds((gu32*)g, (su32*)(As + p2 * 16384 + rb * 64), 16, 0, 0);
    }
  };
  auto STAGE_B = [&](int p2, int t) {
    #pragma unroll
    for (int j = 0; j < 4; ++j) {
      const int rb = j * 64 + wv * 8;
      const u16* g = Bb + (size_t)(n0 + rb + srow) * ldb + t * 64 + sksw;
      __builtin_amdgcn_global_load_lds((gu32*)g, (su32*)(Bs + p2 * 16384 + rb * 64), 16, 0, 0);
    }
  };

  STAGE_A(0, 0); STAGE_B(0, 0);
  if (nk > 1) { STAGE_A(1, 1); STAGE_B(1, 1); }

  for (int kt = 0; kt < nk; ++kt) {
    const int p = kt & 1;
    if (kt + 1 < nk) asm volatile("s_waitcnt vmcnt(8)" ::: "memory");
    else             asm volatile("s_waitcnt vmcnt(0)" ::: "memory");
    BAR();

    const u16* Asl = As + p * 16384;
    const u16* Bsl = Bs + p * 16384;
    const bool st = (kt + 2) < nk;
    const int ps = (kt + 2) & 1;

    bf16x8 aV[2][4], bLo[2][2], bHi[2][2];

    // ---- ph0: a(mh0), b(nh0) ----
    #pragma unroll
    for (int ks = 0; ks < 2; ++ks) {
      const int ro = ks ? rdsw1 : rdsw0;
      #pragma unroll
      for (int i = 0; i < 4; ++i)
        aV[ks][i] = *(const bf16x8*)(Asl + (wm + i * 16 + lr) * 64 + ro);
      #pragma unroll
      for (int i = 0; i < 2; ++i)
        bLo[ks][i] = *(const bf16x8*)(Bsl + (wn + i * 16 + lr) * 64 + ro);
    }
    BAR();
    __builtin_amdgcn_s_setprio(1);
    QMFMA(aV, bLo, 0, 0);
    __builtin_amdgcn_s_setprio(0);
    BAR();

    // ---- ph1: b(nh1) ----
    #pragma unroll
    for (int ks = 0; ks < 2; ++ks) {
      const int ro = ks ? rdsw1 : rdsw0;
      #pragma unroll
      for (int i = 0; i < 2; ++i)
        bHi[ks][i] = *(const bf16x8*)(Bsl + (wn + 32 + i * 16 + lr) * 64 + ro);
    }
    BAR();
    __builtin_amdgcn_s_setprio(1);
    QMFMA(aV, bHi, 0, 2);
    __builtin_amdgcn_s_setprio(0);
    BAR();

    // ---- ph2: a(mh1); stage B(kt+2) ----
    #pragma unroll
    for (int ks = 0; ks < 2; ++ks) {
      const int ro = ks ? rdsw1 : rdsw0;
      #pragma unroll
      for (int i = 0; i < 4; ++i)
        aV[ks][i] = *(const bf16x8*)(Asl + (wm + 64 + i * 16 + lr) * 64 + ro);
    }
    if (st) STAGE_B(ps, kt + 2);
    BAR();
    __builtin_amdgcn_s_setprio(1);
    QMFMA(aV, bLo, 4, 0);
    __builtin_amdgcn_s_setprio(0);
    BAR();

    // ---- ph3: stage A(kt+2) ----
    if (st) STAGE_A(ps, kt + 2);
    BAR();
    __builtin_amdgcn_s_setprio(1);
    QMFMA(aV, bHi, 4, 2);
    __builtin_amdgcn_s_setprio(0);
    BAR();
  }

  // epilogue: D row = 4*lg + r, col = lr within each 16x16 fragment
  u16*   C16 = (u16*)Cg + (size_t)b * sC;
  float* C32 = (float*)Cg + (size_t)b * sC;
  const float* xb = (EPI == EP_FINAL) ? (ep_x + (size_t)b * sX) : nullptr;
  #pragma unroll
  for (int mf = 0; mf < 8; ++mf) {
    #pragma unroll
    for (int nf = 0; nf < 4; ++nf) {
      #pragma unroll
      for (int r = 0; r < 4; ++r) {
        int row = m0 + wm + mf * 16 + lg * 4 + r;
        int col = n0 + wn + nf * 16 + lr;
        float v = acc[mf][nf][r];
        if constexpr (EPI == EP_FG) {
          v = v * ep_scale[col] + ep_bias[col];
          if (col < 1024) v = fmaxf(v, 0.f);
          C16[(size_t)row * ldc + col] = f2bf(v);
        } else if constexpr (EPI == EP_SCALE16) {
          C16[(size_t)row * ldc + col] = f2bf(v);
        } else {
          v += ep_bias[row] + xb[(size_t)row * ldc + col];
          C32[(size_t)row * ldc + col] = v;
        }
      }
    }
  }
}

// -------- softmax: wave-per-row, no block sync. bf16 scores -> f32 attn + bf16 P ------
__global__ __launch_bounds__(256) void softmax_k(u16* __restrict__ SP, float* __restrict__ attn) {
  const int l = threadIdx.x & 63;
  const size_t row = (size_t)blockIdx.x * 4 + (threadIdx.x >> 6);
  u16* sp = SP + row * N_;
  float* ar = attn + row * N_;

  u16x8 s[4];
  #pragma unroll
  for (int j = 0; j < 4; ++j) s[j] = *(const u16x8*)&sp[j * 512 + l * 8];
  u16x4 st4 = *(const u16x4*)&sp[2048 + l * 4];

  float v[4][8], t[4];
  float mx = -3.0e38f;
  #pragma unroll
  for (int j = 0; j < 4; ++j)
    #pragma unroll
    for (int e = 0; e < 8; ++e) { v[j][e] = bf2f(s[j][e]); mx = fmaxf(mx, v[j][e]); }
  #pragma unroll
  for (int e = 0; e < 4; ++e) { t[e] = bf2f(st4[e]); mx = fmaxf(mx, t[e]); }
  #pragma unroll
  for (int o = 32; o; o >>= 1) mx = fmaxf(mx, __shfl_xor(mx, o));

  float sum = 0.f;
  #pragma unroll
  for (int j = 0; j < 4; ++j)
    #pragma unroll
    for (int e = 0; e < 8; ++e) { v[j][e] = __expf(v[j][e] - mx); sum += v[j][e]; }
  #pragma unroll
  for (int e = 0; e < 4; ++e) { t[e] = __expf(t[e] - mx); sum += t[e]; }
  #pragma unroll
  for (int o = 32; o; o >>= 1) sum += __shfl_xor(sum, o);
  const float inv = 1.0f / sum;

  #pragma unroll
  for (int j = 0; j < 4; ++j) {
    float4 lo = {v[j][0] * inv, v[j][1] * inv, v[j][2] * inv, v[j][3] * inv};
    float4 hi = {v[j][4] * inv, v[j][5] * inv, v[j][6] * inv, v[j][7] * inv};
    *(float4*)&ar[j * 512 + l * 8] = lo;
    *(float4*)&ar[j * 512 + l * 8 + 4] = hi;
    u16x8 p8;
    p8[0]=f2bf(lo.x); p8[1]=f2bf(lo.y); p8[2]=f2bf(lo.z); p8[3]=f2bf(lo.w);
    p8[4]=f2bf(hi.x); p8[5]=f2bf(hi.y); p8[6]=f2bf(hi.z); p8[7]=f2bf(hi.w);
    *(u16x8*)&sp[j * 512 + l * 8] = p8;
  }
  float4 tl = {t[0] * inv, t[1] * inv, t[2] * inv, t[3] * inv};
  *(float4*)&ar[2048 + l * 4] = tl;
  u16x4 p4; p4[0]=f2bf(tl.x); p4[1]=f2bf(tl.y); p4[2]=f2bf(tl.z); p4[3]=f2bf(tl.w);
  *(u16x4*)&sp[2048 + l * 4] = p4;
}

// ---------------- launch ----------------
extern "C" void kernel_launch(void* const* d_in, const int* in_sizes, int n_in,
                              void* d_out, int out_size, void* d_ws, size_t ws_size,
                              hipStream_t stream) {
  const float* x    = (const float*)d_in[0];
  const float* f_w  = (const float*)d_in[1];
  const float* f_b  = (const float*)d_in[2];
  const float* f_ga = (const float*)d_in[3];
  const float* f_be = (const float*)d_in[4];
  const float* f_me = (const float*)d_in[5];
  const float* f_va = (const float*)d_in[6];
  const float* g_w  = (const float*)d_in[7];
  const float* g_b  = (const float*)d_in[8];
  const float* g_ga = (const float*)d_in[9];
  const float* g_be = (const float*)d_in[10];
  const float* g_me = (const float*)d_in[11];
  const float* g_va = (const float*)d_in[12];
  const float* h_w  = (const float*)d_in[13];
  const float* h_b  = (const float*)d_in[14];
  const float* v_w  = (const float*)d_in[15];
  const float* v_b  = (const float*)d_in[16];

  float* out0 = (float*)d_out;
  float* attn = out0 + (size_t)B_ * C_ * N_;   // second output region

  // workspace carve
  char* p = (char*)d_ws;
  u16* xT   = (u16*)p; p += (size_t)B_ * N_ * C_ * 2;       // 75.5 MB
  u16* fghT = (u16*)p; p += (size_t)B_ * N_ * 1536 * 2;     // 56.6 MB
  u16* hx   = (u16*)p; p += (size_t)B_ * MID_ * N_ * 2;     // 18.9 MB
  u16* ZT   = (u16*)p; p += (size_t)B_ * N_ * MID_ * 2;     // 18.9 MB
  u16* Wall = (u16*)p; p += (size_t)1536 * C_ * 2;          // 6.3 MB
  u16* vwb  = (u16*)p; p += (size_t)C_ * MID_ * 2;          // 2.1 MB
  float* sc = (float*)p; p += 1536 * 4;
  float* bi = (float*)p; p += 1536 * 4;
  p = (char*)(((size_t)p + 255) & ~(size_t)255);
  u16* SP   = (u16*)p; p += (size_t)B_ * N_ * N_ * 2;       // 85 MB bf16 scores -> P

  hipFuncSetAttribute((const void*)gemm5_kernel<EP_FG, 0, 6, 9>,      hipFuncAttributeMaxDynamicSharedMemorySize, 131072);
  hipFuncSetAttribute((const void*)gemm5_kernel<EP_SCALE16, 2, 9, 9>, hipFuncAttributeMaxDynamicSharedMemorySize, 131072);
  hipFuncSetAttribute((const void*)gemm5_kernel<EP_SCALE16, 0, 2, 9>, hipFuncAttributeMaxDynamicSharedMemorySize, 131072);
  hipFuncSetAttribute((const void*)gemm5_kernel<EP_FINAL, 1, 9, 8>,   hipFuncAttributeMaxDynamicSharedMemorySize, 131072);

  prep_all_k<<<2048, 256, 0, stream>>>(f_w, g_w, h_w, v_w,
                                       f_b, f_ga, f_be, f_me, f_va,
                                       g_b, g_ga, g_be, g_me, g_va, h_b,
                                       Wall, vwb, sc, bi);
  transpose_x_k<<<dim3(N_ / 64, C_ / 64, B_), 256, 0, stream>>>(x, xT);

  // G1: fghT[n][c'] = xT[n][:].Wall[c'][:] (M=2304,N=1536,K=2048); share A-panel along x
  gemm5_kernel<EP_FG, 0, 6, 9><<<dim3(6 * 9 * 8), 512, 131072, stream>>>(
      xT, C_, (long long)N_ * C_, Wall, C_, 0,
      fghT, 1536, (long long)N_ * 1536, C_, sc, bi, nullptr, 0);

  // hx[c][n] = fghT[n][1024+c]
  transpose_h_k<<<dim3(N_ / 64, MID_ / 64, B_), 256, 0, stream>>>(fghT, hx);

  // G2: scores bf16 = f.g^T (fscale folded into f) (M=N=2304,K=512); 3x3 XCD groups
  gemm5_kernel<EP_SCALE16, 2, 9, 9><<<dim3(9 * 9 * 8), 512, 131072, stream>>>(
      fghT, 1536, (long long)N_ * 1536, fghT + 512, 1536, (long long)N_ * 1536,
      SP, N_, (long long)N_ * N_, MID_, nullptr, nullptr, nullptr, 0);

  // softmax: wave-per-row (18432 rows), writes attn f32 + P bf16 in place
  softmax_k<<<(B_ * N_) / 4, 256, 0, stream>>>(SP, attn);

  // G3: ZT[n][c] = P[n][:].hx[c][:] (M=2304,N=512,K=2304); share A(P)-panel along x
  gemm5_kernel<EP_SCALE16, 0, 2, 9><<<dim3(2 * 9 * 8), 512, 131072, stream>>>(
      SP, N_, (long long)N_ * N_, hx, N_, (long long)MID_ * N_,
      ZT, MID_, (long long)N_ * MID_, N_, nullptr, nullptr, nullptr, 0);

  // G5: out[o][n] = vwb[o][:].ZT[n][:] + v_b[o] + x[o][n] (M=2048,N=2304,K=512); share B along y
  gemm5_kernel<EP_FINAL, 1, 9, 8><<<dim3(9 * 8 * 8), 512, 131072, stream>>>(
      vwb, MID_, 0, ZT, MID_, (long long)N_ * MID_,
      out0, N_, (long long)C_ * N_, MID_, nullptr, v_b, x, (long long)C_ * N_);
}

// Round 9
// 489.177 us; speedup vs baseline: 1.0868x; 1.0309x over previous
//
#include <hip/hip_runtime.h>
#include <math.h>

typedef unsigned short u16;
typedef unsigned short u16x4 __attribute__((ext_vector_type(4)));
typedef unsigned short u16x8 __attribute__((ext_vector_type(8)));
typedef __bf16 bf16x8 __attribute__((ext_vector_type(8)));
typedef float f32x4 __attribute__((ext_vector_type(4)));

typedef __attribute__((address_space(1))) const unsigned int gu32;
typedef __attribute__((address_space(3))) unsigned int su32;

#define B_ 8
#define C_ 2048
#define MID_ 512
#define N_ 2304

#define BAR() do { asm volatile("" ::: "memory"); __builtin_amdgcn_s_barrier(); asm volatile("" ::: "memory"); } while (0)

#define QMFMA(AV, BV, MO, NO)                                                             \
  { _Pragma("unroll") for (int mfi = 0; mfi < 4; ++mfi) {                                 \
      _Pragma("unroll") for (int nfi = 0; nfi < 2; ++nfi) {                               \
        acc[MO + mfi][NO + nfi] = __builtin_amdgcn_mfma_f32_16x16x32_bf16(                \
            AV[0][mfi], BV[0][nfi], acc[MO + mfi][NO + nfi], 0, 0, 0);                    \
        acc[MO + mfi][NO + nfi] = __builtin_amdgcn_mfma_f32_16x16x32_bf16(                \
            AV[1][mfi], BV[1][nfi], acc[MO + mfi][NO + nfi], 0, 0, 0); } } }

static __device__ __forceinline__ u16 f2bf(float f) {
  union { float f; unsigned u; } c; c.f = f;
  unsigned u = c.u;
  u += 0x7fffu + ((u >> 16) & 1u);   // round to nearest even
  return (u16)(u >> 16);
}
static __device__ __forceinline__ float bf2f(u16 x) {
  union { unsigned u; float f; } c; c.u = ((unsigned)x) << 16; return c.f;
}

// ------- fused: x-transpose (blocks 0..9215) + weight/BN prep (blocks 9216..11263) ----
__global__ __launch_bounds__(256) void txp_k(
    const float* __restrict__ x, u16* __restrict__ xT,
    const float* __restrict__ fw, const float* __restrict__ gw,
    const float* __restrict__ hw, const float* __restrict__ vw,
    const float* fb, const float* fg, const float* fbe, const float* fm, const float* fv,
    const float* gb, const float* gg, const float* gbe, const float* gm, const float* gv,
    const float* hb,
    u16* __restrict__ wall, u16* __restrict__ vwb,
    float* __restrict__ scale, float* __restrict__ bias) {
  __shared__ float tile[64][68];
  const int bid = blockIdx.x;
  if (bid < 9216) {
    // x [B][C][N] f32 -> xT [B][N][C] bf16, 64x64 tile
    const int n0 = (bid % 36) * 64, c0 = ((bid / 36) % 32) * 64, b = bid / 1152;
    const float* xb = x + (size_t)b * C_ * N_;
    u16* xTb = xT + (size_t)b * N_ * C_;
    const int r = threadIdx.x >> 2, q = threadIdx.x & 3;
    #pragma unroll
    for (int j = 0; j < 4; ++j) {
      float4 v = *(const float4*)&xb[(size_t)(c0 + r) * N_ + n0 + (q + 4 * j) * 4];
      *(float4*)&tile[r][(q + 4 * j) * 4] = v;
    }
    __syncthreads();
    #pragma unroll
    for (int g = 0; g < 2; ++g) {
      const int cl = (q * 2 + g) * 8;
      u16x8 w;
      #pragma unroll
      for (int e = 0; e < 8; ++e) w[e] = f2bf(tile[cl + e][r]);
      *(u16x8*)&xTb[(size_t)(n0 + r) * C_ + c0 + cl] = w;
    }
  } else {
    const int gid = (bid - 9216) * 256 + threadIdx.x;
    if (gid < 393216) {                       // 1536*2048/8 u16x8 chunks of Wall
      int e = gid * 8; int r = e >> 11;
      const float* s = (r < 512) ? (fw + e) : (r < 1024) ? (gw + e - (512 << 11)) : (hw + e - (1024 << 11));
      float4 v0 = *(const float4*)s, v1 = *(const float4*)(s + 4);
      u16x8 w;
      w[0]=f2bf(v0.x); w[1]=f2bf(v0.y); w[2]=f2bf(v0.z); w[3]=f2bf(v0.w);
      w[4]=f2bf(v1.x); w[5]=f2bf(v1.y); w[6]=f2bf(v1.z); w[7]=f2bf(v1.w);
      *(u16x8*)&wall[e] = w;
    } else if (gid < 524288) {                // + 2048*512/8 vwb
      int e = (gid - 393216) * 8;
      float4 v0 = *(const float4*)(vw + e), v1 = *(const float4*)(vw + e + 4);
      u16x8 w;
      w[0]=f2bf(v0.x); w[1]=f2bf(v0.y); w[2]=f2bf(v0.z); w[3]=f2bf(v0.w);
      w[4]=f2bf(v1.x); w[5]=f2bf(v1.y); w[6]=f2bf(v1.z); w[7]=f2bf(v1.w);
      *(u16x8*)&vwb[e] = w;
    }
    if (gid < 1536) {
      const float FS = 0.044194173824159216f;  // 512^-0.5 folded into f columns
      int i = gid;
      if (i < 512) {
        float inv = fg[i] / sqrtf(fv[i] + 1e-5f);
        scale[i] = inv * FS; bias[i] = (fb[i] * inv + fbe[i] - fm[i] * inv) * FS;
      } else if (i < 1024) {
        int j = i - 512;
        float inv = gg[j] / sqrtf(gv[j] + 1e-5f);
        scale[i] = inv; bias[i] = gb[j] * inv + gbe[j] - gm[j] * inv;
      } else {
        scale[i] = 1.0f; bias[i] = hb[i - 1024];
      }
    }
  }
}

// ---------------- GEMM: 256x256, BK=64, 2-buf LDS, 4-phase, counted vmcnt, XCD groups --
// OUT[M,N] = A[M,K] * B^T[N,K]; bf16 row-major contiguous-K.
// bf16 epilogues route acc through the DEAD LDS buffer (wave-private 4KB ping-pong,
// no barrier needed) -> full-128B-line global stores instead of 2B scatter.
#define EP_FG 0       // v*scale[col]+bias[col], relu if col<1024, store bf16
#define EP_SCALE16 1  // f2bf(v)
#define EP_FINAL 2    // v+bias[row]+x[row][col], store f32

template<int EPI, int SWZ, int GX, int GY>
__global__ __launch_bounds__(512, 2) void gemm5_kernel(
    const u16* __restrict__ Ag, int lda, long long sA,
    const u16* __restrict__ Bg, int ldb, long long sB,
    void* __restrict__ Cg, int ldc, long long sC, int K,
    const float* __restrict__ ep_scale, const float* __restrict__ ep_bias,
    const float* __restrict__ ep_x, long long sX)
{
  extern __shared__ __align__(16) u16 smem[];
  u16* As = smem;                    // [2][256*64]
  u16* Bs = smem + 2 * 256 * 64;

  int tx, ty, tz;
  {
    const int L = blockIdx.x;
    const int xcd = L & 7, r = L >> 3;
    if constexpr (SWZ == 0) {
      const int i = r % GX, j = (r / GX) * 8 + xcd;
      tx = i; ty = j % GY; tz = j / GY;
    } else if constexpr (SWZ == 1) {
      const int i = r % GY, j = (r / GY) * 8 + xcd;
      ty = i; tx = j % GX; tz = j / GX;
    } else {
      const int i = r % 9, jg = (r / 9) * 8 + xcd;
      const int bx = jg % (GX / 3), rem = jg / (GX / 3);
      const int by = rem % (GY / 3); tz = rem / (GY / 3);
      tx = bx * 3 + i % 3; ty = by * 3 + i / 3;
    }
  }

  const int tid = threadIdx.x;
  const int lane = tid & 63;
  const int wv = tid >> 6;
  const int b = tz;
  const int m0 = ty * 256;
  const int n0 = tx * 256;
  const int wm = (wv >> 2) * 128;
  const int wn = (wv & 3) * 64;
  const int lr = lane & 15, lg = lane >> 4;

  const u16* Ab = Ag + (size_t)b * sA;
  const u16* Bb = Bg + (size_t)b * sB;
  const int nk = K >> 6;

  const int srow = lane >> 3;
  const int sksw = ((lane & 7) ^ srow) * 8;
  const int rdsw0 = ((0 + lg) ^ (lr & 7)) * 8;
  const int rdsw1 = ((4 + lg) ^ (lr & 7)) * 8;

  f32x4 acc[8][4];
  #pragma unroll
  for (int i = 0; i < 8; ++i)
    #pragma unroll
    for (int j = 0; j < 4; ++j)
      acc[i][j] = f32x4{0.f, 0.f, 0.f, 0.f};

  auto STAGE_A = [&](int p2, int t) {
    #pragma unroll
    for (int j = 0; j < 4; ++j) {
      const int rb = j * 64 + wv * 8;
      const u16* g = Ab + (size_t)(m0 + rb + srow) * lda + t * 64 + sksw;
      __builtin_amdgcn_global_load_lds((gu32*)g, (su32*)(As + p2 * 16384 + rb * 64), 16, 0, 0);
    }
  };
  auto STAGE_B = [&](int p2, int t) {
    #pragma unroll
    for (int j = 0; j < 4; ++j) {
      const int rb = j * 64 + wv * 8;
      const u16* g = Bb + (size_t)(n0 + rb + srow) * ldb + t * 64 + sksw;
      __builtin_amdgcn_global_load_lds((gu32*)g, (su32*)(Bs + p2 * 16384 + rb * 64), 16, 0, 0);
    }
  };

  STAGE_A(0, 0); STAGE_B(0, 0);
  if (nk > 1) { STAGE_A(1, 1); STAGE_B(1, 1); }

  for (int kt = 0; kt < nk; ++kt) {
    const int p = kt & 1;
    if (kt + 1 < nk) asm volatile("s_waitcnt vmcnt(8)" ::: "memory");
    else             asm volatile("s_waitcnt vmcnt(0)" ::: "memory");
    BAR();

    const u16* Asl = As + p * 16384;
    const u16* Bsl = Bs + p * 16384;
    const bool st = (kt + 2) < nk;
    const int ps = (kt + 2) & 1;

    bf16x8 aV[2][4], bLo[2][2], bHi[2][2];

    // ---- ph0: a(mh0), b(nh0) ----
    #pragma unroll
    for (int ks = 0; ks < 2; ++ks) {
      const int ro = ks ? rdsw1 : rdsw0;
      #pragma unroll
      for (int i = 0; i < 4; ++i)
        aV[ks][i] = *(const bf16x8*)(Asl + (wm + i * 16 + lr) * 64 + ro);
      #pragma unroll
      for (int i = 0; i < 2; ++i)
        bLo[ks][i] = *(const bf16x8*)(Bsl + (wn + i * 16 + lr) * 64 + ro);
    }
    BAR();
    __builtin_amdgcn_s_setprio(1);
    QMFMA(aV, bLo, 0, 0);
    __builtin_amdgcn_s_setprio(0);
    BAR();

    // ---- ph1: b(nh1) ----
    #pragma unroll
    for (int ks = 0; ks < 2; ++ks) {
      const int ro = ks ? rdsw1 : rdsw0;
      #pragma unroll
      for (int i = 0; i < 2; ++i)
        bHi[ks][i] = *(const bf16x8*)(Bsl + (wn + 32 + i * 16 + lr) * 64 + ro);
    }
    BAR();
    __builtin_amdgcn_s_setprio(1);
    QMFMA(aV, bHi, 0, 2);
    __builtin_amdgcn_s_setprio(0);
    BAR();

    // ---- ph2: a(mh1); stage B(kt+2) ----
    #pragma unroll
    for (int ks = 0; ks < 2; ++ks) {
      const int ro = ks ? rdsw1 : rdsw0;
      #pragma unroll
      for (int i = 0; i < 4; ++i)
        aV[ks][i] = *(const bf16x8*)(Asl + (wm + 64 + i * 16 + lr) * 64 + ro);
    }
    if (st) STAGE_B(ps, kt + 2);
    BAR();
    __builtin_amdgcn_s_setprio(1);
    QMFMA(aV, bLo, 4, 0);
    __builtin_amdgcn_s_setprio(0);
    BAR();

    // ---- ph3: stage A(kt+2) ----
    if (st) STAGE_A(ps, kt + 2);
    BAR();
    __builtin_amdgcn_s_setprio(1);
    QMFMA(aV, bHi, 4, 2);
    __builtin_amdgcn_s_setprio(0);
    BAR();
  }

  // epilogue: D row = 4*lg + r, col = lr within each 16x16 fragment
  u16*   C16 = (u16*)Cg + (size_t)b * sC;
  float* C32 = (float*)Cg + (size_t)b * sC;
  if constexpr (EPI == EP_FINAL) {
    const float* xb = ep_x + (size_t)b * sX;
    #pragma unroll
    for (int mf = 0; mf < 8; ++mf) {
      #pragma unroll
      for (int nf = 0; nf < 4; ++nf) {
        #pragma unroll
        for (int r = 0; r < 4; ++r) {
          int row = m0 + wm + mf * 16 + lg * 4 + r;
          int col = n0 + wn + nf * 16 + lr;
          float v = acc[mf][nf][r] + ep_bias[row] + xb[(size_t)row * ldc + col];
          C32[(size_t)row * ldc + col] = v;
        }
      }
    }
  } else {
    // bf16 path: stage 16x64 row-chunk in DEAD LDS buffer (wave-private), store full lines.
    // Dead buffer: (nk-1)&1 ^ 1 — last staged at kt=nk-4, last read kt=nk-2, all waves
    // past its trailing barrier; vmcnt(0) drained. 8 waves x 4KB ping-pong = 32KB = buf.
    const int plo = ((nk - 1) & 1) ^ 1;
    u16* scr = As + plo * 16384 + wv * 2048;
    const int r_ = lane & 15, seg = lane >> 4;
    #pragma unroll
    for (int mf = 0; mf < 8; ++mf) {
      u16* h = scr + (mf & 1) * 1024;
      #pragma unroll
      for (int nf = 0; nf < 4; ++nf) {
        #pragma unroll
        for (int r = 0; r < 4; ++r) {
          int col = n0 + wn + nf * 16 + lr;
          float v = acc[mf][nf][r];
          if constexpr (EPI == EP_FG) {
            v = v * ep_scale[col] + ep_bias[col];
            if (col < 1024) v = fmaxf(v, 0.f);
          }
          h[(lg * 4 + r) * 64 + nf * 16 + lr] = f2bf(v);
        }
      }
      asm volatile("s_waitcnt lgkmcnt(0)" ::: "memory");
      __builtin_amdgcn_sched_barrier(0);
      u16x8 w0 = *(const u16x8*)(h + r_ * 64 + seg * 16);
      u16x8 w1 = *(const u16x8*)(h + r_ * 64 + seg * 16 + 8);
      u16* dst = C16 + (size_t)(m0 + wm + mf * 16 + r_) * ldc + (n0 + wn + seg * 16);
      *(u16x8*)dst = w0;
      *(u16x8*)(dst + 8) = w1;
    }
  }
}

// ---- fused: softmax (blocks 0..4607) + h-transpose (blocks 4608..6911) --------------
// softmax: wave-per-row, bf16 scores SP -> f32 attn + bf16 P in place.
// th: fghT h-cols [B][N][1024+c] -> hx [B][512][N], 64x64 tile.
__global__ __launch_bounds__(256) void softmax_th_k(
    u16* __restrict__ SP, float* __restrict__ attn,
    const u16* __restrict__ fghT, u16* __restrict__ hx) {
  __shared__ u16 tile[64][72];
  const int bid = blockIdx.x;
  if (bid < 4608) {
    const int l = threadIdx.x & 63;
    const size_t row = (size_t)bid * 4 + (threadIdx.x >> 6);
    u16* sp = SP + row * N_;
    float* ar = attn + row * N_;
    u16x8 s[4];
    #pragma unroll
    for (int j = 0; j < 4; ++j) s[j] = *(const u16x8*)&sp[j * 512 + l * 8];
    u16x4 st4 = *(const u16x4*)&sp[2048 + l * 4];
    float v[4][8], t[4];
    float mx = -3.0e38f;
    #pragma unroll
    for (int j = 0; j < 4; ++j)
      #pragma unroll
      for (int e = 0; e < 8; ++e) { v[j][e] = bf2f(s[j][e]); mx = fmaxf(mx, v[j][e]); }
    #pragma unroll
    for (int e = 0; e < 4; ++e) { t[e] = bf2f(st4[e]); mx = fmaxf(mx, t[e]); }
    #pragma unroll
    for (int o = 32; o; o >>= 1) mx = fmaxf(mx, __shfl_xor(mx, o));
    float sum = 0.f;
    #pragma unroll
    for (int j = 0; j < 4; ++j)
      #pragma unroll
      for (int e = 0; e < 8; ++e) { v[j][e] = __expf(v[j][e] - mx); sum += v[j][e]; }
    #pragma unroll
    for (int e = 0; e < 4; ++e) { t[e] = __expf(t[e] - mx); sum += t[e]; }
    #pragma unroll
    for (int o = 32; o; o >>= 1) sum += __shfl_xor(sum, o);
    const float inv = 1.0f / sum;
    #pragma unroll
    for (int j = 0; j < 4; ++j) {
      float4 lo = {v[j][0] * inv, v[j][1] * inv, v[j][2] * inv, v[j][3] * inv};
      float4 hi = {v[j][4] * inv, v[j][5] * inv, v[j][6] * inv, v[j][7] * inv};
      *(float4*)&ar[j * 512 + l * 8] = lo;
      *(float4*)&ar[j * 512 + l * 8 + 4] = hi;
      u16x8 p8;
      p8[0]=f2bf(lo.x); p8[1]=f2bf(lo.y); p8[2]=f2bf(lo.z); p8[3]=f2bf(lo.w);
      p8[4]=f2bf(hi.x); p8[5]=f2bf(hi.y); p8[6]=f2bf(hi.z); p8[7]=f2bf(hi.w);
      *(u16x8*)&sp[j * 512 + l * 8] = p8;
    }
    float4 tl = {t[0] * inv, t[1] * inv, t[2] * inv, t[3] * inv};
    *(float4*)&ar[2048 + l * 4] = tl;
    u16x4 p4; p4[0]=f2bf(tl.x); p4[1]=f2bf(tl.y); p4[2]=f2bf(tl.z); p4[3]=f2bf(tl.w);
    *(u16x4*)&sp[2048 + l * 4] = p4;
  } else {
    const int t = bid - 4608;
    const int n0 = (t % 36) * 64, c0 = ((t / 36) % 8) * 64, b = t / 288;
    const u16* src = fghT + (size_t)b * N_ * 1536;
    u16* dst = hx + (size_t)b * MID_ * N_;
    const int r = threadIdx.x >> 2, q = threadIdx.x & 3;
    #pragma unroll
    for (int g = 0; g < 2; ++g) {
      const int cl = q * 16 + g * 8;
      *(u16x8*)&tile[r][cl] = *(const u16x8*)&src[(size_t)(n0 + r) * 1536 + 1024 + c0 + cl];
    }
    __syncthreads();
    #pragma unroll
    for (int g = 0; g < 2; ++g) {
      const int cl = q * 16 + g * 8;
      u16x8 w;
      #pragma unroll
      for (int e = 0; e < 8; ++e) w[e] = tile[cl + e][r];
      *(u16x8*)&dst[(size_t)(c0 + r) * N_ + n0 + cl] = w;
    }
  }
}

// ---------------- launch ----------------
extern "C" void kernel_launch(void* const* d_in, const int* in_sizes, int n_in,
                              void* d_out, int out_size, void* d_ws, size_t ws_size,
                              hipStream_t stream) {
  const float* x    = (const float*)d_in[0];
  const float* f_w  = (const float*)d_in[1];
  const float* f_b  = (const float*)d_in[2];
  const float* f_ga = (const float*)d_in[3];
  const float* f_be = (const float*)d_in[4];
  const float* f_me = (const float*)d_in[5];
  const float* f_va = (const float*)d_in[6];
  const float* g_w  = (const float*)d_in[7];
  const float* g_b  = (const float*)d_in[8];
  const float* g_ga = (const float*)d_in[9];
  const float* g_be = (const float*)d_in[10];
  const float* g_me = (const float*)d_in[11];
  const float* g_va = (const float*)d_in[12];
  const float* h_w  = (const float*)d_in[13];
  const float* h_b  = (const float*)d_in[14];
  const float* v_w  = (const float*)d_in[15];
  const float* v_b  = (const float*)d_in[16];

  float* out0 = (float*)d_out;
  float* attn = out0 + (size_t)B_ * C_ * N_;   // second output region

  // workspace carve
  char* p = (char*)d_ws;
  u16* xT   = (u16*)p; p += (size_t)B_ * N_ * C_ * 2;       // 75.5 MB
  u16* fghT = (u16*)p; p += (size_t)B_ * N_ * 1536 * 2;     // 56.6 MB
  u16* hx   = (u16*)p; p += (size_t)B_ * MID_ * N_ * 2;     // 18.9 MB
  u16* ZT   = (u16*)p; p += (size_t)B_ * N_ * MID_ * 2;     // 18.9 MB
  u16* Wall = (u16*)p; p += (size_t)1536 * C_ * 2;          // 6.3 MB
  u16* vwb  = (u16*)p; p += (size_t)C_ * MID_ * 2;          // 2.1 MB
  float* sc = (float*)p; p += 1536 * 4;
  float* bi = (float*)p; p += 1536 * 4;
  p = (char*)(((size_t)p + 255) & ~(size_t)255);
  u16* SP   = (u16*)p; p += (size_t)B_ * N_ * N_ * 2;       // 85 MB bf16 scores -> P

  hipFuncSetAttribute((const void*)gemm5_kernel<EP_FG, 0, 6, 9>,      hipFuncAttributeMaxDynamicSharedMemorySize, 131072);
  hipFuncSetAttribute((const void*)gemm5_kernel<EP_SCALE16, 2, 9, 9>, hipFuncAttributeMaxDynamicSharedMemorySize, 131072);
  hipFuncSetAttribute((const void*)gemm5_kernel<EP_SCALE16, 0, 2, 9>, hipFuncAttributeMaxDynamicSharedMemorySize, 131072);
  hipFuncSetAttribute((const void*)gemm5_kernel<EP_FINAL, 1, 9, 8>,   hipFuncAttributeMaxDynamicSharedMemorySize, 131072);

  // fused transpose_x + prep (9216 + 2048 blocks)
  txp_k<<<11264, 256, 0, stream>>>(x, xT, f_w, g_w, h_w, v_w,
                                   f_b, f_ga, f_be, f_me, f_va,
                                   g_b, g_ga, g_be, g_me, g_va, h_b,
                                   Wall, vwb, sc, bi);

  // G1: fghT[n][c'] = xT[n][:].Wall[c'][:] (M=2304,N=1536,K=2048); share A-panel along x
  gemm5_kernel<EP_FG, 0, 6, 9><<<dim3(6 * 9 * 8), 512, 131072, stream>>>(
      xT, C_, (long long)N_ * C_, Wall, C_, 0,
      fghT, 1536, (long long)N_ * 1536, C_, sc, bi, nullptr, 0);

  // G2: scores bf16 = f.g^T (fscale folded into f) (M=N=2304,K=512); 3x3 XCD groups
  gemm5_kernel<EP_SCALE16, 2, 9, 9><<<dim3(9 * 9 * 8), 512, 131072, stream>>>(
      fghT, 1536, (long long)N_ * 1536, fghT + 512, 1536, (long long)N_ * 1536,
      SP, N_, (long long)N_ * N_, MID_, nullptr, nullptr, nullptr, 0);

  // fused softmax (4608 blocks) + h-transpose (2304 blocks)
  softmax_th_k<<<6912, 256, 0, stream>>>(SP, attn, fghT, hx);

  // G3: ZT[n][c] = P[n][:].hx[c][:] (M=2304,N=512,K=2304); share A(P)-panel along x
  gemm5_kernel<EP_SCALE16, 0, 2, 9><<<dim3(2 * 9 * 8), 512, 131072, stream>>>(
      SP, N_, (long long)N_ * N_, hx, N_, (long long)MID_ * N_,
      ZT, MID_, (long long)N_ * MID_, N_, nullptr, nullptr, nullptr, 0);

  // G5: out[o][n] = vwb[o][:].ZT[n][:] + v_b[o] + x[o][n] (M=2048,N=2304,K=512); share B along y
  gemm5_kernel<EP_FINAL, 1, 9, 8><<<dim3(9 * 8 * 8), 512, 131072, stream>>>(
      vwb, MID_, 0, ZT, MID_, (long long)N_ * MID_,
      out0, N_, (long long)C_ * N_, MID_, nullptr, v_b, x, (long long)C_ * N_);
}

// Round 10
// 483.999 us; speedup vs baseline: 1.0985x; 1.0107x over previous
//
#include <hip/hip_runtime.h>
#include <math.h>

typedef unsigned short u16;
typedef unsigned short u16x4 __attribute__((ext_vector_type(4)));
typedef unsigned short u16x8 __attribute__((ext_vector_type(8)));
typedef __bf16 bf16x8 __attribute__((ext_vector_type(8)));
typedef float f32x16 __attribute__((ext_vector_type(16)));

typedef __attribute__((address_space(1))) const unsigned int gu32;
typedef __attribute__((address_space(3))) unsigned int su32;

#define B_ 8
#define C_ 2048
#define MID_ 512
#define N_ 2304

#define BAR() do { asm volatile("" ::: "memory"); __builtin_amdgcn_s_barrier(); asm volatile("" ::: "memory"); } while (0)

static __device__ __forceinline__ u16 f2bf(float f) {
  union { float f; unsigned u; } c; c.f = f;
  unsigned u = c.u;
  u += 0x7fffu + ((u >> 16) & 1u);   // round to nearest even
  return (u16)(u >> 16);
}
static __device__ __forceinline__ float bf2f(u16 x) {
  union { unsigned u; float f; } c; c.u = ((unsigned)x) << 16; return c.f;
}

// ------- fused: x-transpose (blocks 0..9215) + weight/BN prep (blocks 9216..11263) ----
__global__ __launch_bounds__(256) void txp_k(
    const float* __restrict__ x, u16* __restrict__ xT,
    const float* __restrict__ fw, const float* __restrict__ gw,
    const float* __restrict__ hw, const float* __restrict__ vw,
    const float* fb, const float* fg, const float* fbe, const float* fm, const float* fv,
    const float* gb, const float* gg, const float* gbe, const float* gm, const float* gv,
    const float* hb,
    u16* __restrict__ wall, u16* __restrict__ vwb,
    float* __restrict__ scale, float* __restrict__ bias) {
  __shared__ float tile[64][68];
  const int bid = blockIdx.x;
  if (bid < 9216) {
    const int n0 = (bid % 36) * 64, c0 = ((bid / 36) % 32) * 64, b = bid / 1152;
    const float* xb = x + (size_t)b * C_ * N_;
    u16* xTb = xT + (size_t)b * N_ * C_;
    const int r = threadIdx.x >> 2, q = threadIdx.x & 3;
    #pragma unroll
    for (int j = 0; j < 4; ++j) {
      float4 v = *(const float4*)&xb[(size_t)(c0 + r) * N_ + n0 + (q + 4 * j) * 4];
      *(float4*)&tile[r][(q + 4 * j) * 4] = v;
    }
    __syncthreads();
    #pragma unroll
    for (int g = 0; g < 2; ++g) {
      const int cl = (q * 2 + g) * 8;
      u16x8 w;
      #pragma unroll
      for (int e = 0; e < 8; ++e) w[e] = f2bf(tile[cl + e][r]);
      *(u16x8*)&xTb[(size_t)(n0 + r) * C_ + c0 + cl] = w;
    }
  } else {
    const int gid = (bid - 9216) * 256 + threadIdx.x;
    if (gid < 393216) {
      int e = gid * 8; int r = e >> 11;
      const float* s = (r < 512) ? (fw + e) : (r < 1024) ? (gw + e - (512 << 11)) : (hw + e - (1024 << 11));
      float4 v0 = *(const float4*)s, v1 = *(const float4*)(s + 4);
      u16x8 w;
      w[0]=f2bf(v0.x); w[1]=f2bf(v0.y); w[2]=f2bf(v0.z); w[3]=f2bf(v0.w);
      w[4]=f2bf(v1.x); w[5]=f2bf(v1.y); w[6]=f2bf(v1.z); w[7]=f2bf(v1.w);
      *(u16x8*)&wall[e] = w;
    } else if (gid < 524288) {
      int e = (gid - 393216) * 8;
      float4 v0 = *(const float4*)(vw + e), v1 = *(const float4*)(vw + e + 4);
      u16x8 w;
      w[0]=f2bf(v0.x); w[1]=f2bf(v0.y); w[2]=f2bf(v0.z); w[3]=f2bf(v0.w);
      w[4]=f2bf(v1.x); w[5]=f2bf(v1.y); w[6]=f2bf(v1.z); w[7]=f2bf(v1.w);
      *(u16x8*)&vwb[e] = w;
    }
    if (gid < 1536) {
      const float FS = 0.044194173824159216f;  // 512^-0.5 folded into f columns
      int i = gid;
      if (i < 512) {
        float inv = fg[i] / sqrtf(fv[i] + 1e-5f);
        scale[i] = inv * FS; bias[i] = (fb[i] * inv + fbe[i] - fm[i] * inv) * FS;
      } else if (i < 1024) {
        int j = i - 512;
        float inv = gg[j] / sqrtf(gv[j] + 1e-5f);
        scale[i] = inv; bias[i] = gb[j] * inv + gbe[j] - gm[j] * inv;
      } else {
        scale[i] = 1.0f; bias[i] = hb[i - 1024];
      }
    }
  }
}

// ------- GEMM: 256x256, BK=64, 2-buf LDS, 4-phase, counted vmcnt, XCD groups ---------
// Engine now uses mfma_f32_32x32x16_bf16 (4061 FLOP/cyc vs 3378 for 16x16x32).
// OUT[M,N] = A[M,K] * B^T[N,K]; bf16 row-major contiguous-K.
// Per-wave 128x64 = 4(m) x 2(n) tiles of 32x32, acc f32x16 each.
// A/B frag: row = lane&31, k = kstep*16 + (lane>>5)*8 + e.
// C/D frag: col = lane&31, row = (reg&3) + 8*(reg>>2) + 4*(lane>>5)  [m74/m101].
#define EP_FG 0       // v*scale[col]+bias[col], relu if col<1024, store bf16
#define EP_SCALE16 1  // f2bf(v)
#define EP_FINAL 2    // v+bias[row]+x[row][col], store f32

template<int EPI, int SWZ, int GX, int GY>
__global__ __launch_bounds__(512, 2) void gemm6_kernel(
    const u16* __restrict__ Ag, int lda, long long sA,
    const u16* __restrict__ Bg, int ldb, long long sB,
    void* __restrict__ Cg, int ldc, long long sC, int K,
    const float* __restrict__ ep_scale, const float* __restrict__ ep_bias,
    const float* __restrict__ ep_x, long long sX)
{
  extern __shared__ __align__(16) u16 smem[];
  u16* As = smem;                    // [2][256*64]
  u16* Bs = smem + 2 * 256 * 64;

  int tx, ty, tz;
  {
    const int L = blockIdx.x;
    const int xcd = L & 7, r = L >> 3;
    if constexpr (SWZ == 0) {
      const int i = r % GX, j = (r / GX) * 8 + xcd;
      tx = i; ty = j % GY; tz = j / GY;
    } else if constexpr (SWZ == 1) {
      const int i = r % GY, j = (r / GY) * 8 + xcd;
      ty = i; tx = j % GX; tz = j / GX;
    } else {
      const int i = r % 9, jg = (r / 9) * 8 + xcd;
      const int bx = jg % (GX / 3), rem = jg / (GX / 3);
      const int by = rem % (GY / 3); tz = rem / (GY / 3);
      tx = bx * 3 + i % 3; ty = by * 3 + i / 3;
    }
  }

  const int tid = threadIdx.x;
  const int lane = tid & 63;
  const int wv = tid >> 6;
  const int b = tz;
  const int m0 = ty * 256;
  const int n0 = tx * 256;
  const int wm = (wv >> 2) * 128;    // 0 / 128
  const int wn = (wv & 3) * 64;      // 0,64,128,192
  const int l31 = lane & 31, l7 = lane & 7, lg2 = lane >> 5;

  const u16* Ab = Ag + (size_t)b * sA;
  const u16* Bb = Bg + (size_t)b * sB;
  const int nk = K >> 6;

  const int srow = lane >> 3;                    // 0..7 == LDS row & 7 at stage
  const int sksw = ((lane & 7) ^ srow) * 8;      // pre-swizzled global k-offset

  f32x16 acc[4][2];
  #pragma unroll
  for (int i = 0; i < 4; ++i)
    #pragma unroll
    for (int j = 0; j < 2; ++j)
      acc[i][j] = (f32x16)(0.f);

  auto STAGE_A = [&](int p2, int t) {
    #pragma unroll
    for (int j = 0; j < 4; ++j) {
      const int rb = j * 64 + wv * 8;
      const u16* g = Ab + (size_t)(m0 + rb + srow) * lda + t * 64 + sksw;
      __builtin_amdgcn_global_load_lds((gu32*)g, (su32*)(As + p2 * 16384 + rb * 64), 16, 0, 0);
    }
  };
  auto STAGE_B = [&](int p2, int t) {
    #pragma unroll
    for (int j = 0; j < 4; ++j) {
      const int rb = j * 64 + wv * 8;
      const u16* g = Bb + (size_t)(n0 + rb + srow) * ldb + t * 64 + sksw;
      __builtin_amdgcn_global_load_lds((gu32*)g, (su32*)(Bs + p2 * 16384 + rb * 64), 16, 0, 0);
    }
  };

  STAGE_A(0, 0); STAGE_B(0, 0);
  if (nk > 1) { STAGE_A(1, 1); STAGE_B(1, 1); }

  for (int kt = 0; kt < nk; ++kt) {
    const int p = kt & 1;
    if (kt + 1 < nk) asm volatile("s_waitcnt vmcnt(8)" ::: "memory");
    else             asm volatile("s_waitcnt vmcnt(0)" ::: "memory");
    BAR();

    const u16* Asl = As + p * 16384;
    const u16* Bsl = Bs + p * 16384;
    const bool st = (kt + 2) < nk;
    const int ps = (kt + 2) & 1;

    bf16x8 aL[4], aH[4], bA[4], bB[4];

    // ---- ph0: A m-tiles 0,1 + B n-tile 0 (12x b128) ----
    #pragma unroll
    for (int ks = 0; ks < 4; ++ks) {
      const int ro = ((ks * 2 + lg2) ^ l7) * 8;
      aL[ks] = *(const bf16x8*)(Asl + (wm + l31) * 64 + ro);
      aH[ks] = *(const bf16x8*)(Asl + (wm + 32 + l31) * 64 + ro);
      bA[ks] = *(const bf16x8*)(Bsl + (wn + l31) * 64 + ro);
    }
    BAR();
    __builtin_amdgcn_s_setprio(1);
    #pragma unroll
    for (int ks = 0; ks < 4; ++ks) {
      acc[0][0] = __builtin_amdgcn_mfma_f32_32x32x16_bf16(aL[ks], bA[ks], acc[0][0], 0, 0, 0);
      acc[1][0] = __builtin_amdgcn_mfma_f32_32x32x16_bf16(aH[ks], bA[ks], acc[1][0], 0, 0, 0);
    }
    __builtin_amdgcn_s_setprio(0);
    BAR();

    // ---- ph1: B n-tile 1 (4x b128) ----
    #pragma unroll
    for (int ks = 0; ks < 4; ++ks) {
      const int ro = ((ks * 2 + lg2) ^ l7) * 8;
      bB[ks] = *(const bf16x8*)(Bsl + (wn + 32 + l31) * 64 + ro);
    }
    BAR();
    __builtin_amdgcn_s_setprio(1);
    #pragma unroll
    for (int ks = 0; ks < 4; ++ks) {
      acc[0][1] = __builtin_amdgcn_mfma_f32_32x32x16_bf16(aL[ks], bB[ks], acc[0][1], 0, 0, 0);
      acc[1][1] = __builtin_amdgcn_mfma_f32_32x32x16_bf16(aH[ks], bB[ks], acc[1][1], 0, 0, 0);
    }
    __builtin_amdgcn_s_setprio(0);
    BAR();

    // ---- ph2: A m-tiles 2,3 (8x b128); stage B(kt+2) ----
    #pragma unroll
    for (int ks = 0; ks < 4; ++ks) {
      const int ro = ((ks * 2 + lg2) ^ l7) * 8;
      aL[ks] = *(const bf16x8*)(Asl + (wm + 64 + l31) * 64 + ro);
      aH[ks] = *(const bf16x8*)(Asl + (wm + 96 + l31) * 64 + ro);
    }
    if (st) STAGE_B(ps, kt + 2);
    BAR();
    __builtin_amdgcn_s_setprio(1);
    #pragma unroll
    for (int ks = 0; ks < 4; ++ks) {
      acc[2][0] = __builtin_amdgcn_mfma_f32_32x32x16_bf16(aL[ks], bA[ks], acc[2][0], 0, 0, 0);
      acc[3][0] = __builtin_amdgcn_mfma_f32_32x32x16_bf16(aH[ks], bA[ks], acc[3][0], 0, 0, 0);
    }
    __builtin_amdgcn_s_setprio(0);
    BAR();

    // ---- ph3: stage A(kt+2) ----
    if (st) STAGE_A(ps, kt + 2);
    BAR();
    __builtin_amdgcn_s_setprio(1);
    #pragma unroll
    for (int ks = 0; ks < 4; ++ks) {
      acc[2][1] = __builtin_amdgcn_mfma_f32_32x32x16_bf16(aL[ks], bB[ks], acc[2][1], 0, 0, 0);
      acc[3][1] = __builtin_amdgcn_mfma_f32_32x32x16_bf16(aH[ks], bB[ks], acc[3][1], 0, 0, 0);
    }
    __builtin_amdgcn_s_setprio(0);
    BAR();
  }

  // epilogue: per 32x32 tile, col = lane&31, row = (reg&3) + 8*(reg>>2) + 4*(lane>>5)
  u16*   C16 = (u16*)Cg + (size_t)b * sC;
  float* C32 = (float*)Cg + (size_t)b * sC;
  const float* xb = (EPI == EP_FINAL) ? (ep_x + (size_t)b * sX) : nullptr;
  #pragma unroll
  for (int mt = 0; mt < 4; ++mt) {
    #pragma unroll
    for (int nt = 0; nt < 2; ++nt) {
      #pragma unroll
      for (int reg = 0; reg < 16; ++reg) {
        int row = m0 + wm + mt * 32 + (reg & 3) + 8 * (reg >> 2) + 4 * lg2;
        int col = n0 + wn + nt * 32 + l31;
        float v = acc[mt][nt][reg];
        if constexpr (EPI == EP_FG) {
          v = v * ep_scale[col] + ep_bias[col];
          if (col < 1024) v = fmaxf(v, 0.f);
          C16[(size_t)row * ldc + col] = f2bf(v);
        } else if constexpr (EPI == EP_SCALE16) {
          C16[(size_t)row * ldc + col] = f2bf(v);
        } else {
          v += ep_bias[row] + xb[(size_t)row * ldc + col];
          C32[(size_t)row * ldc + col] = v;
        }
      }
    }
  }
}

// ---- fused: softmax (blocks 0..4607) + h-transpose (blocks 4608..6911) --------------
__global__ __launch_bounds__(256) void softmax_th_k(
    u16* __restrict__ SP, float* __restrict__ attn,
    const u16* __restrict__ fghT, u16* __restrict__ hx) {
  __shared__ u16 tile[64][72];
  const int bid = blockIdx.x;
  if (bid < 4608) {
    const int l = threadIdx.x & 63;
    const size_t row = (size_t)bid * 4 + (threadIdx.x >> 6);
    u16* sp = SP + row * N_;
    float* ar = attn + row * N_;
    u16x8 s[4];
    #pragma unroll
    for (int j = 0; j < 4; ++j) s[j] = *(const u16x8*)&sp[j * 512 + l * 8];
    u16x4 st4 = *(const u16x4*)&sp[2048 + l * 4];
    float v[4][8], t[4];
    float mx = -3.0e38f;
    #pragma unroll
    for (int j = 0; j < 4; ++j)
      #pragma unroll
      for (int e = 0; e < 8; ++e) { v[j][e] = bf2f(s[j][e]); mx = fmaxf(mx, v[j][e]); }
    #pragma unroll
    for (int e = 0; e < 4; ++e) { t[e] = bf2f(st4[e]); mx = fmaxf(mx, t[e]); }
    #pragma unroll
    for (int o = 32; o; o >>= 1) mx = fmaxf(mx, __shfl_xor(mx, o));
    float sum = 0.f;
    #pragma unroll
    for (int j = 0; j < 4; ++j)
      #pragma unroll
      for (int e = 0; e < 8; ++e) { v[j][e] = __expf(v[j][e] - mx); sum += v[j][e]; }
    #pragma unroll
    for (int e = 0; e < 4; ++e) { t[e] = __expf(t[e] - mx); sum += t[e]; }
    #pragma unroll
    for (int o = 32; o; o >>= 1) sum += __shfl_xor(sum, o);
    const float inv = 1.0f / sum;
    #pragma unroll
    for (int j = 0; j < 4; ++j) {
      float4 lo = {v[j][0] * inv, v[j][1] * inv, v[j][2] * inv, v[j][3] * inv};
      float4 hi = {v[j][4] * inv, v[j][5] * inv, v[j][6] * inv, v[j][7] * inv};
      *(float4*)&ar[j * 512 + l * 8] = lo;
      *(float4*)&ar[j * 512 + l * 8 + 4] = hi;
      u16x8 p8;
      p8[0]=f2bf(lo.x); p8[1]=f2bf(lo.y); p8[2]=f2bf(lo.z); p8[3]=f2bf(lo.w);
      p8[4]=f2bf(hi.x); p8[5]=f2bf(hi.y); p8[6]=f2bf(hi.z); p8[7]=f2bf(hi.w);
      *(u16x8*)&sp[j * 512 + l * 8] = p8;
    }
    float4 tl = {t[0] * inv, t[1] * inv, t[2] * inv, t[3] * inv};
    *(float4*)&ar[2048 + l * 4] = tl;
    u16x4 p4; p4[0]=f2bf(tl.x); p4[1]=f2bf(tl.y); p4[2]=f2bf(tl.z); p4[3]=f2bf(tl.w);
    *(u16x4*)&sp[2048 + l * 4] = p4;
  } else {
    const int t = bid - 4608;
    const int n0 = (t % 36) * 64, c0 = ((t / 36) % 8) * 64, b = t / 288;
    const u16* src = fghT + (size_t)b * N_ * 1536;
    u16* dst = hx + (size_t)b * MID_ * N_;
    const int r = threadIdx.x >> 2, q = threadIdx.x & 3;
    #pragma unroll
    for (int g = 0; g < 2; ++g) {
      const int cl = q * 16 + g * 8;
      *(u16x8*)&tile[r][cl] = *(const u16x8*)&src[(size_t)(n0 + r) * 1536 + 1024 + c0 + cl];
    }
    __syncthreads();
    #pragma unroll
    for (int g = 0; g < 2; ++g) {
      const int cl = q * 16 + g * 8;
      u16x8 w;
      #pragma unroll
      for (int e = 0; e < 8; ++e) w[e] = tile[cl + e][r];
      *(u16x8*)&dst[(size_t)(c0 + r) * N_ + n0 + cl] = w;
    }
  }
}

// ---------------- launch ----------------
extern "C" void kernel_launch(void* const* d_in, const int* in_sizes, int n_in,
                              void* d_out, int out_size, void* d_ws, size_t ws_size,
                              hipStream_t stream) {
  const float* x    = (const float*)d_in[0];
  const float* f_w  = (const float*)d_in[1];
  const float* f_b  = (const float*)d_in[2];
  const float* f_ga = (const float*)d_in[3];
  const float* f_be = (const float*)d_in[4];
  const float* f_me = (const float*)d_in[5];
  const float* f_va = (const float*)d_in[6];
  const float* g_w  = (const float*)d_in[7];
  const float* g_b  = (const float*)d_in[8];
  const float* g_ga = (const float*)d_in[9];
  const float* g_be = (const float*)d_in[10];
  const float* g_me = (const float*)d_in[11];
  const float* g_va = (const float*)d_in[12];
  const float* h_w  = (const float*)d_in[13];
  const float* h_b  = (const float*)d_in[14];
  const float* v_w  = (const float*)d_in[15];
  const float* v_b  = (const float*)d_in[16];

  float* out0 = (float*)d_out;
  float* attn = out0 + (size_t)B_ * C_ * N_;   // second output region

  // workspace carve
  char* p = (char*)d_ws;
  u16* xT   = (u16*)p; p += (size_t)B_ * N_ * C_ * 2;       // 75.5 MB
  u16* fghT = (u16*)p; p += (size_t)B_ * N_ * 1536 * 2;     // 56.6 MB
  u16* hx   = (u16*)p; p += (size_t)B_ * MID_ * N_ * 2;     // 18.9 MB
  u16* ZT   = (u16*)p; p += (size_t)B_ * N_ * MID_ * 2;     // 18.9 MB
  u16* Wall = (u16*)p; p += (size_t)1536 * C_ * 2;          // 6.3 MB
  u16* vwb  = (u16*)p; p += (size_t)C_ * MID_ * 2;          // 2.1 MB
  float* sc = (float*)p; p += 1536 * 4;
  float* bi = (float*)p; p += 1536 * 4;
  p = (char*)(((size_t)p + 255) & ~(size_t)255);
  u16* SP   = (u16*)p; p += (size_t)B_ * N_ * N_ * 2;       // 85 MB bf16 scores -> P

  hipFuncSetAttribute((const void*)gemm6_kernel<EP_FG, 0, 6, 9>,      hipFuncAttributeMaxDynamicSharedMemorySize, 131072);
  hipFuncSetAttribute((const void*)gemm6_kernel<EP_SCALE16, 2, 9, 9>, hipFuncAttributeMaxDynamicSharedMemorySize, 131072);
  hipFuncSetAttribute((const void*)gemm6_kernel<EP_SCALE16, 0, 2, 9>, hipFuncAttributeMaxDynamicSharedMemorySize, 131072);
  hipFuncSetAttribute((const void*)gemm6_kernel<EP_FINAL, 1, 9, 8>,   hipFuncAttributeMaxDynamicSharedMemorySize, 131072);

  // fused transpose_x + prep (9216 + 2048 blocks)
  txp_k<<<11264, 256, 0, stream>>>(x, xT, f_w, g_w, h_w, v_w,
                                   f_b, f_ga, f_be, f_me, f_va,
                                   g_b, g_ga, g_be, g_me, g_va, h_b,
                                   Wall, vwb, sc, bi);

  // G1: fghT[n][c'] = xT[n][:].Wall[c'][:] (M=2304,N=1536,K=2048); share A-panel along x
  gemm6_kernel<EP_FG, 0, 6, 9><<<dim3(6 * 9 * 8), 512, 131072, stream>>>(
      xT, C_, (long long)N_ * C_, Wall, C_, 0,
      fghT, 1536, (long long)N_ * 1536, C_, sc, bi, nullptr, 0);

  // G2: scores bf16 = f.g^T (fscale folded into f) (M=N=2304,K=512); 3x3 XCD groups
  gemm6_kernel<EP_SCALE16, 2, 9, 9><<<dim3(9 * 9 * 8), 512, 131072, stream>>>(
      fghT, 1536, (long long)N_ * 1536, fghT + 512, 1536, (long long)N_ * 1536,
      SP, N_, (long long)N_ * N_, MID_, nullptr, nullptr, nullptr, 0);

  // fused softmax (4608 blocks) + h-transpose (2304 blocks)
  softmax_th_k<<<6912, 256, 0, stream>>>(SP, attn, fghT, hx);

  // G3: ZT[n][c] = P[n][:].hx[c][:] (M=2304,N=512,K=2304); share A(P)-panel along x
  gemm6_kernel<EP_SCALE16, 0, 2, 9><<<dim3(2 * 9 * 8), 512, 131072, stream>>>(
      SP, N_, (long long)N_ * N_, hx, N_, (long long)MID_ * N_,
      ZT, MID_, (long long)N_ * MID_, N_, nullptr, nullptr, nullptr, 0);

  // G5: out[o][n] = vwb[o][:].ZT[n][:] + v_b[o] + x[o][n] (M=2048,N=2304,K=512); share B along y
  gemm6_kernel<EP_FINAL, 1, 9, 8><<<dim3(9 * 8 * 8), 512, 131072, stream>>>(
      vwb, MID_, 0, ZT, MID_, (long long)N_ * MID_,
      out0, N_, (long long)C_ * N_, MID_, nullptr, v_b, x, (long long)C_ * N_);
}